// Round 11
// baseline (2911.035 us; speedup 1.0000x reference)
//
#include <hip/hip_runtime.h>

#define BATCH   64
#define TSTEPS  256
#define NINPUT  512
#define HDIM    1024
#define G4      4096   // 4*HDIM
#define NSCAN   64     // scan WGs per layer
#define NHC     16     // h-columns per scan WG
#define NGEMM   128    // persistent gemm WGs

typedef __attribute__((ext_vector_type(8))) short short8;
typedef __attribute__((ext_vector_type(4))) float f32x4;
typedef __attribute__((ext_vector_type(4))) unsigned int u32x4;
typedef __attribute__((ext_vector_type(2))) unsigned int u32x2;

static __device__ __forceinline__ unsigned short f2bf(float x) {
    unsigned u = __float_as_uint(x);
    unsigned r = 0x7fffu + ((u >> 16) & 1u);
    return (unsigned short)((u + r) >> 16);
}
static __device__ __forceinline__ float bf2f(unsigned short b) {
    return __uint_as_float(((unsigned)b) << 16);
}
static __device__ __forceinline__ float sigf(float x) {
    return 1.f / (1.f + __expf(-x));
}
static __device__ __forceinline__ float tanhf_fast(float x) {
    return 2.f / (1.f + __expf(-2.f * x)) - 1.f;
}

// ---------------- poison ring with bf16-NaN sentinel ----------------
__global__ void k_poison(u32x4* __restrict__ p, long n4) {
    long i = (long)blockIdx.x * blockDim.x + threadIdx.x;
    long st = (long)gridDim.x * blockDim.x;
    u32x4 v = (u32x4){0xFFFFFFFFu, 0xFFFFFFFFu, 0xFFFFFFFFu, 0xFFFFFFFFu};
    for (; i < n4; i += st) p[i] = v;
}

// ---------------- float -> bf16 (linear, for weights) ----------------
__global__ void k_f2b(const float* __restrict__ in, unsigned short* __restrict__ out, long n) {
    long i = (long)blockIdx.x * blockDim.x + threadIdx.x;
    long stride = (long)gridDim.x * blockDim.x;
    for (long j = i * 4; j < n; j += stride * 4) {
        float4 v = *reinterpret_cast<const float4*>(in + j);
        ushort4 o;
        o.x = f2bf(v.x); o.y = f2bf(v.y); o.z = f2bf(v.z); o.w = f2bf(v.w);
        *reinterpret_cast<ushort4*>(out + j) = o;
    }
}

// ---------------- float -> bf16 with [B][T] -> [T][B] transpose ----------------
__global__ void k_f2b_tm(const float* __restrict__ in, unsigned short* __restrict__ out) {
    const long total = (long)BATCH * TSTEPS * NINPUT;
    long v = ((long)blockIdx.x * blockDim.x + threadIdx.x) * 4;
    const long stride = (long)gridDim.x * blockDim.x * 4;
    for (; v < total; v += stride) {
        long row = v / NINPUT;                 // b*T + t
        int i = (int)(v - row * NINPUT);
        int b = (int)(row / TSTEPS);
        int t = (int)(row - (long)b * TSTEPS);
        float4 f = *reinterpret_cast<const float4*>(in + v);
        ushort4 o;
        o.x = f2bf(f.x); o.y = f2bf(f.y); o.z = f2bf(f.z); o.w = f2bf(f.w);
        *reinterpret_cast<ushort4*>(out + ((size_t)t * BATCH + b) * NINPUT + i) = o;
    }
}

// ---------------- bias combine + h0 init ----------------
__global__ void k_prep_small(const float* __restrict__ bih0, const float* __restrict__ bhh0,
                             const float* __restrict__ bih1, const float* __restrict__ bhh1,
                             float* __restrict__ bb0, float* __restrict__ bb1,
                             const float* __restrict__ h0,
                             unsigned short* __restrict__ hA0, unsigned short* __restrict__ hA1) {
    int i = blockIdx.x * blockDim.x + threadIdx.x;
    if (i < G4) { bb0[i] = bih0[i] + bhh0[i]; bb1[i] = bih1[i] + bhh1[i]; }
    if (i < BATCH * HDIM) {
        hA0[i] = f2bf(h0[i]);
        hA1[i] = f2bf(h0[BATCH * HDIM + i]);
    }
}

// ---------------- standalone bf16 GEMM (layer-0 input projection) ----------------
#define BM 128
#define BN 128
#define BK 64

static __device__ __forceinline__ void g2l16(const unsigned short* g, void* lds) {
    __builtin_amdgcn_global_load_lds(
        (const __attribute__((address_space(1))) unsigned int*)g,
        (__attribute__((address_space(3))) unsigned int*)lds, 16, 0, 0);
}

__global__ __launch_bounds__(256)
void k_gemm_bt(const unsigned short* __restrict__ A,
               const unsigned short* __restrict__ B,
               const float* __restrict__ bias,
               unsigned short* __restrict__ C,
               int M, int N, int K)
{
    __shared__ unsigned short As[BM * BK];
    __shared__ unsigned short Bs[BN * BK];
    const int tid = threadIdx.x;
    const int lane = tid & 63, wv = tid >> 6;
    const int nbn = N / BN;
    const int bm0 = (blockIdx.x / nbn) * BM;
    const int bn0 = (blockIdx.x % nbn) * BN;
    const int wr = wv >> 1, wc = wv & 1;

    f32x4 acc[4][4];
#pragma unroll
    for (int i = 0; i < 4; i++)
#pragma unroll
        for (int j = 0; j < 4; j++) acc[i][j] = (f32x4){0.f, 0.f, 0.f, 0.f};

    const int srow = tid >> 3;
    const int scb  = (tid & 7) * 16;

    for (int kt = 0; kt < K; kt += BK) {
        __syncthreads();
#pragma unroll
        for (int is = 0; is < 4; is++) {
            int row = is * 32 + srow;
            int kb = scb ^ ((row & 7) << 4);
            g2l16(A + (size_t)(bm0 + row) * K + kt + (kb >> 1),
                  (char*)As + is * 4096 + wv * 1024);
        }
#pragma unroll
        for (int is = 0; is < 4; is++) {
            int row = is * 32 + srow;
            int kb = scb ^ ((row & 7) << 4);
            g2l16(B + (size_t)(bn0 + row) * K + kt + (kb >> 1),
                  (char*)Bs + is * 4096 + wv * 1024);
        }
        asm volatile("s_waitcnt vmcnt(0)" ::: "memory");
        __syncthreads();

#pragma unroll
        for (int ks = 0; ks < 2; ks++) {
            short8 a[4], b[4];
            const int kb = ks * 64 + ((lane >> 4) << 4);
#pragma unroll
            for (int mt = 0; mt < 4; mt++) {
                int r = wr * 64 + mt * 16 + (lane & 15);
                a[mt] = *reinterpret_cast<const short8*>(
                    (const char*)As + r * 128 + (kb ^ ((r & 7) << 4)));
            }
#pragma unroll
            for (int nt = 0; nt < 4; nt++) {
                int n = wc * 64 + nt * 16 + (lane & 15);
                b[nt] = *reinterpret_cast<const short8*>(
                    (const char*)Bs + n * 128 + (kb ^ ((n & 7) << 4)));
            }
#pragma unroll
            for (int mt = 0; mt < 4; mt++)
#pragma unroll
                for (int nt = 0; nt < 4; nt++)
                    acc[mt][nt] = __builtin_amdgcn_mfma_f32_16x16x32_bf16(
                        a[mt], b[nt], acc[mt][nt], 0, 0, 0);
        }
    }

#pragma unroll
    for (int nt = 0; nt < 4; nt++) {
        int cg = bn0 + wc * 64 + nt * 16 + (lane & 15);
        float bv = bias[cg];
#pragma unroll
        for (int mt = 0; mt < 4; mt++) {
#pragma unroll
            for (int e = 0; e < 4; e++) {
                int rg = bm0 + wr * 64 + mt * 16 + ((lane >> 4) << 2) + e;
                C[(size_t)rg * N + cg] = f2bf(acc[mt][nt][e] + bv);
            }
        }
    }
}

// =====================================================================
// Fused pipeline: scan0 (WG 0-63) | gemm1 (WG 64-191) | scan1 (WG 192-255)
// Time-major: xw rows = t*64+b; ring slot t = [64][1024] bf16 contiguous.
// Both scans: full-T sentinel rings. Retry = optimistic full load first;
// on failure, cheap 1-dword/lane probe loop (traffic 2KB vs 8MB aggregate)
// until sentinel-free, then full load (which still fully validates).
// =====================================================================

template<int L>
static __device__ void scan_body(const unsigned short* __restrict__ whh,
                                 const unsigned short* __restrict__ xw,
                                 const float* __restrict__ c0,
                                 const unsigned short* __restrict__ h0b,
                                 unsigned short* __restrict__ ring,   // [T][64][1024] bf16, poisoned
                                 float* __restrict__ hn, float* __restrict__ cn,
                                 const unsigned* __restrict__ gflags,
                                 int wg, char* smem)
{
    float (*plds)[64][34] = reinterpret_cast<float (*)[64][34]>(smem);
    const int tid = threadIdx.x;
    const int lane = tid & 63, kw = tid >> 6;
    const int colbase = wg * NHC;
    const int cb = wg >> 3;     // n-tile sub-index for gemm flags

    short8 bfr[4][8];
    {
        const int c = lane & 15;
#pragma unroll
        for (int g = 0; g < 4; g++) {
            int grow = g * HDIM + colbase + c;
#pragma unroll
            for (int s = 0; s < 8; s++) {
                int k = kw * 256 + s * 32 + ((lane >> 4) << 3);
                bfr[g][s] = *reinterpret_cast<const short8*>(whh + (size_t)grow * HDIM + k);
            }
        }
    }

    const int r2 = tid >> 2;
    const int u0 = (tid & 3) * 4;
    f32x4 cst = *reinterpret_cast<const f32x4*>(c0 + (size_t)r2 * HDIM + colbase + u0);

    const int arow = lane & 15;
    const size_t koff = (size_t)kw * 256 + ((lane >> 4) << 3);
    int wm = 0;   // L==1: gemm m-tiles complete through wm-1

    for (int t = 0; t < TSTEPS; t++) {
        // ---- xw for this step ----
        const unsigned short* xp = xw + ((size_t)t * BATCH + r2) * G4 + colbase + u0;
        u32x2 xi, xf, xg, xo;
        if (L == 0) {
            xi = *reinterpret_cast<const u32x2*>(xp);
            xf = *reinterpret_cast<const u32x2*>(xp + HDIM);
            xg = *reinterpret_cast<const u32x2*>(xp + 2 * HDIM);
            xo = *reinterpret_cast<const u32x2*>(xp + 3 * HDIM);
        } else {
            const int mt = t >> 1;
            while (mt >= wm) {
                int mti = wm + (lane >> 2); if (mti > 127) mti = 127;
                const unsigned* fp = gflags + mti * 32 + (lane & 3) * 8 + cb;
                unsigned v;
                asm volatile("global_load_dword %0, %1, off sc0 sc1" : "=v"(v) : "v"(fp));
                asm volatile("s_waitcnt vmcnt(0)" ::: "memory");
                __builtin_amdgcn_sched_barrier(0);
                unsigned long long mk = __ballot(v != 0);
                int adv = 0;
                while (adv < 16 && ((mk >> (4 * adv)) & 0xFull) == 0xFull) adv++;
                wm += adv;
                if (adv == 0) __builtin_amdgcn_s_sleep(16);
            }
            asm volatile("global_load_dwordx2 %0, %1, off sc0 sc1" : "=v"(xi) : "v"(xp));
            asm volatile("global_load_dwordx2 %0, %1, off sc0 sc1" : "=v"(xf) : "v"(xp + HDIM));
            asm volatile("global_load_dwordx2 %0, %1, off sc0 sc1" : "=v"(xg) : "v"(xp + 2 * HDIM));
            asm volatile("global_load_dwordx2 %0, %1, off sc0 sc1" : "=v"(xo) : "v"(xp + 3 * HDIM));
        }

        // ---- h(t-1) fragment base ----
        const unsigned short* pa0;
        if (t == 0) pa0 = h0b + (size_t)arow * HDIM + koff;
        else        pa0 = ring + ((size_t)(t - 1) * BATCH + arow) * HDIM + koff;
        const unsigned short* pa1 = pa0 + 16 * HDIM;
        const unsigned short* pa2 = pa0 + 32 * HDIM;
        const unsigned short* pa3 = pa0 + 48 * HDIM;
        // cheap-probe address: one dword per producer WG (batch 63, col 16*lane)
        const unsigned short* pp =
            ring + ((size_t)(t - 1) * BATCH + 63) * HDIM + lane * 16;

        // ---- optimistic full load; failed rounds poll the cheap probe ----
        u32x4 afr[8][4];
#define ISSUE4(S, OFFS) \
        asm volatile("global_load_dwordx4 %0, %1, off offset:" OFFS " sc0 sc1" : "=v"(afr[S][0]) : "v"(pa0)); \
        asm volatile("global_load_dwordx4 %0, %1, off offset:" OFFS " sc0 sc1" : "=v"(afr[S][1]) : "v"(pa1)); \
        asm volatile("global_load_dwordx4 %0, %1, off offset:" OFFS " sc0 sc1" : "=v"(afr[S][2]) : "v"(pa2)); \
        asm volatile("global_load_dwordx4 %0, %1, off offset:" OFFS " sc0 sc1" : "=v"(afr[S][3]) : "v"(pa3));
        for (int att = 0; ; att++) {
            if (att > 0) {            // t>0 guaranteed here (t==0 passes att 0)
                for (;;) {
                    unsigned v;
                    asm volatile("global_load_dword %0, %1, off sc0 sc1" : "=v"(v) : "v"(pp));
                    asm volatile("s_waitcnt vmcnt(0)" ::: "memory");
                    __builtin_amdgcn_sched_barrier(0);
                    if (!__any(v >= 0xFFFF0000u)) break;
                    __builtin_amdgcn_s_sleep(2);
                }
            }
            ISSUE4(0, "0")   ISSUE4(1, "64")  ISSUE4(2, "128") ISSUE4(3, "192")
            ISSUE4(4, "256") ISSUE4(5, "320") ISSUE4(6, "384") ISSUE4(7, "448")
            asm volatile("s_waitcnt vmcnt(0)" ::: "memory");
            __builtin_amdgcn_sched_barrier(0);
            unsigned mx = 0;
#pragma unroll
            for (int s = 0; s < 8; s++)
#pragma unroll
                for (int m = 0; m < 4; m++) {
                    u32x4 u = afr[s][m];
                    unsigned a = u[0] > u[1] ? u[0] : u[1];
                    unsigned b = u[2] > u[3] ? u[2] : u[3];
                    unsigned c = a > b ? a : b;
                    mx = mx > c ? mx : c;
                }
            if (!__any(mx >= 0xFFFF0000u)) break;
        }
#undef ISSUE4

        // ---- MFMA ----
        f32x4 acc[4][4];
#pragma unroll
        for (int m = 0; m < 4; m++)
#pragma unroll
            for (int g = 0; g < 4; g++) acc[m][g] = (f32x4){0.f, 0.f, 0.f, 0.f};
#pragma unroll
        for (int s = 0; s < 8; s++)
#pragma unroll
            for (int m = 0; m < 4; m++) {
                short8 av = __builtin_bit_cast(short8, afr[s][m]);
#pragma unroll
                for (int g = 0; g < 4; g++)
                    acc[m][g] = __builtin_amdgcn_mfma_f32_16x16x32_bf16(
                        av, bfr[g][s], acc[m][g], 0, 0, 0);
            }

        // ---- pass A (gates i,f) ----
#pragma unroll
        for (int m = 0; m < 4; m++)
#pragma unroll
            for (int g = 0; g < 2; g++) {
                int col = g * 16 + (lane & 15);
                int rb = m * 16 + ((lane >> 4) << 2);
#pragma unroll
                for (int e = 0; e < 4; e++)
                    plds[kw][rb + e][col] = acc[m][g][e];
            }
        __syncthreads();
        f32x4 sI = (f32x4){0.f,0.f,0.f,0.f}, sF = sI;
#pragma unroll
        for (int w = 0; w < 4; w++) {
            sI += *reinterpret_cast<const f32x4*>(&plds[w][r2][u0]);
            sF += *reinterpret_cast<const f32x4*>(&plds[w][r2][16 + u0]);
        }
        __syncthreads();
        // ---- pass B (gates g,o) ----
#pragma unroll
        for (int m = 0; m < 4; m++)
#pragma unroll
            for (int g = 2; g < 4; g++) {
                int col = (g - 2) * 16 + (lane & 15);
                int rb = m * 16 + ((lane >> 4) << 2);
#pragma unroll
                for (int e = 0; e < 4; e++)
                    plds[kw][rb + e][col] = acc[m][g][e];
            }
        __syncthreads();
        f32x4 sG = (f32x4){0.f,0.f,0.f,0.f}, sO = sG;
#pragma unroll
        for (int w = 0; w < 4; w++) {
            sG += *reinterpret_cast<const f32x4*>(&plds[w][r2][u0]);
            sO += *reinterpret_cast<const f32x4*>(&plds[w][r2][16 + u0]);
        }
        __syncthreads();

#define ADDX(S, V) { unsigned lo = V[0], hi = V[1]; \
        S[0] += bf2f((unsigned short)lo); S[1] += bf2f((unsigned short)(lo >> 16)); \
        S[2] += bf2f((unsigned short)hi); S[3] += bf2f((unsigned short)(hi >> 16)); }
        ADDX(sI, xi) ADDX(sF, xf) ADDX(sG, xg) ADDX(sO, xo)
#undef ADDX

        float hv[4];
#pragma unroll
        for (int j = 0; j < 4; j++) {
            float c = sigf(sF[j]) * cst[j] + sigf(sI[j]) * tanhf_fast(sG[j]);
            cst[j] = c;
            hv[j] = sigf(sO[j]) * tanhf_fast(c);
        }
        u32x2 hp;
        hp[0] = (unsigned)f2bf(hv[0]) | ((unsigned)f2bf(hv[1]) << 16);
        hp[1] = (unsigned)f2bf(hv[2]) | ((unsigned)f2bf(hv[3]) << 16);
        unsigned short* wp = ring + ((size_t)t * BATCH + r2) * HDIM + colbase + u0;
        asm volatile("global_store_dwordx2 %0, %1, off sc0 sc1"
                     :: "v"(wp), "v"(hp) : "memory");

        if (t == TSTEPS - 1) {
            const size_t hi_ = (size_t)r2 * HDIM + colbase + u0;
            *reinterpret_cast<f32x4*>(hn + hi_) = (f32x4){hv[0], hv[1], hv[2], hv[3]};
            *reinterpret_cast<f32x4*>(cn + hi_) = cst;
        }
    }
}

// ---- persistent gemm body: xw1 = ring0 @ w1ib^T + bb1, t-ordered jobs, flags ----
static __device__ void gemm_body(const unsigned short* __restrict__ A,    // ring0
                                 const unsigned short* __restrict__ B,    // w1ib
                                 const float* __restrict__ bias,
                                 unsigned short* __restrict__ C,          // xw (in-place)
                                 unsigned* __restrict__ gflags,
                                 int gw, char* smem)
{
    unsigned short* As = reinterpret_cast<unsigned short*>(smem);
    unsigned short* Bs = As + BM * BK;
    const int tid = threadIdx.x;
    const int lane = tid & 63, wv = tid >> 6;
    const int wr = wv >> 1, wc = wv & 1;
    const int srow = tid >> 3;
    const int scb  = (tid & 7) * 16;

    for (int i = 0; i < 32; i++) {
        const int j = i * NGEMM + gw;
        const int mt = j >> 5;
        const int nt = j & 31;
        const int bm0 = mt * BM, bn0 = nt * BN;

        {
            const unsigned short* lr = A + ((size_t)bm0 + 127) * HDIM + lane * 16;
            for (;;) {
                unsigned v;
                asm volatile("global_load_dword %0, %1, off sc0 sc1" : "=v"(v) : "v"(lr));
                asm volatile("s_waitcnt vmcnt(0)" ::: "memory");
                __builtin_amdgcn_sched_barrier(0);
                if (!__any(v >= 0xFFFF0000u)) break;
                __builtin_amdgcn_s_sleep(64);
            }
        }

        f32x4 acc[4][4];
#pragma unroll
        for (int a = 0; a < 4; a++)
#pragma unroll
            for (int b = 0; b < 4; b++) acc[a][b] = (f32x4){0.f, 0.f, 0.f, 0.f};

        for (int kt = 0; kt < HDIM; kt += BK) {
            __syncthreads();
#pragma unroll
            for (int is = 0; is < 4; is++) {
                int row = is * 32 + srow;
                int kb = scb ^ ((row & 7) << 4);
                g2l16(B + (size_t)(bn0 + row) * HDIM + kt + (kb >> 1),
                      (char*)Bs + is * 4096 + wv * 1024);
            }
            const unsigned short* ap[4];
#pragma unroll
            for (int is = 0; is < 4; is++) {
                int row = is * 32 + srow;
                int kb = scb ^ ((row & 7) << 4);
                ap[is] = A + (size_t)(bm0 + row) * HDIM + kt + (kb >> 1);
            }
            u32x4 av0, av1, av2, av3;
            for (;;) {
                asm volatile("global_load_dwordx4 %0, %1, off sc0 sc1" : "=v"(av0) : "v"(ap[0]));
                asm volatile("global_load_dwordx4 %0, %1, off sc0 sc1" : "=v"(av1) : "v"(ap[1]));
                asm volatile("global_load_dwordx4 %0, %1, off sc0 sc1" : "=v"(av2) : "v"(ap[2]));
                asm volatile("global_load_dwordx4 %0, %1, off sc0 sc1" : "=v"(av3) : "v"(ap[3]));
                asm volatile("s_waitcnt vmcnt(0)" ::: "memory");
                __builtin_amdgcn_sched_barrier(0);
                unsigned mx = 0;
#pragma unroll
                for (int e = 0; e < 4; e++) {
                    unsigned a01 = av0[e] > av1[e] ? av0[e] : av1[e];
                    unsigned a23 = av2[e] > av3[e] ? av2[e] : av3[e];
                    unsigned m = a01 > a23 ? a01 : a23;
                    mx = mx > m ? mx : m;
                }
                if (mx < 0xFFFF0000u) break;
                __builtin_amdgcn_s_sleep(8);
            }
            char* asb = (char*)As;
            *reinterpret_cast<u32x4*>(asb + 0 * 4096 + wv * 1024 + lane * 16) = av0;
            *reinterpret_cast<u32x4*>(asb + 1 * 4096 + wv * 1024 + lane * 16) = av1;
            *reinterpret_cast<u32x4*>(asb + 2 * 4096 + wv * 1024 + lane * 16) = av2;
            *reinterpret_cast<u32x4*>(asb + 3 * 4096 + wv * 1024 + lane * 16) = av3;
            __syncthreads();

#pragma unroll
            for (int ks = 0; ks < 2; ks++) {
                short8 a[4], b[4];
                const int kb = ks * 64 + ((lane >> 4) << 4);
#pragma unroll
                for (int m = 0; m < 4; m++) {
                    int r = wr * 64 + m * 16 + (lane & 15);
                    a[m] = *reinterpret_cast<const short8*>(
                        (const char*)As + r * 128 + (kb ^ ((r & 7) << 4)));
                }
#pragma unroll
                for (int n = 0; n < 4; n++) {
                    int nn = wc * 64 + n * 16 + (lane & 15);
                    b[n] = *reinterpret_cast<const short8*>(
                        (const char*)Bs + nn * 128 + (kb ^ ((nn & 7) << 4)));
                }
#pragma unroll
                for (int m = 0; m < 4; m++)
#pragma unroll
                    for (int n = 0; n < 4; n++)
                        acc[m][n] = __builtin_amdgcn_mfma_f32_16x16x32_bf16(
                            a[m], b[n], acc[m][n], 0, 0, 0);
            }
        }

#pragma unroll
        for (int n = 0; n < 4; n++) {
            int cg = bn0 + wc * 64 + n * 16 + (lane & 15);
            float bv = bias[cg];
#pragma unroll
            for (int m = 0; m < 4; m++) {
#pragma unroll
                for (int e = 0; e < 4; e++) {
                    int rg = bm0 + wr * 64 + m * 16 + ((lane >> 4) << 2) + e;
                    unsigned val = f2bf(acc[m][n][e] + bv);
                    const unsigned short* cp = C + (size_t)rg * G4 + cg;
                    asm volatile("global_store_short %0, %1, off sc0 sc1"
                                 :: "v"(cp), "v"(val) : "memory");
                }
            }
        }
        asm volatile("s_waitcnt vmcnt(0)" ::: "memory");
        __syncthreads();
        if (tid == 0) {
            unsigned one = 1;
            asm volatile("global_store_dword %0, %1, off sc0 sc1"
                         :: "v"(gflags + mt * 32 + nt), "v"(one) : "memory");
        }
    }
}

__global__ __launch_bounds__(256, 1)
void k_fused(const unsigned short* __restrict__ w0hb,
             const unsigned short* __restrict__ w1hb,
             const unsigned short* __restrict__ w1ib,
             const float* __restrict__ bb1,
             unsigned short* __restrict__ xw,
             unsigned short* __restrict__ ring0,
             unsigned short* __restrict__ ring1,
             const float* __restrict__ c0,
             const unsigned short* __restrict__ hA0,
             const unsigned short* __restrict__ hA1,
             float* __restrict__ hn, float* __restrict__ cn,
             unsigned* __restrict__ gflags)
{
    __shared__ alignas(16) char smem[4 * 64 * 34 * 4];
    const int bid = blockIdx.x;
    if (bid < NSCAN) {
        scan_body<0>(w0hb, xw, c0, hA0, ring0, hn, cn, nullptr, bid, smem);
    } else if (bid < NSCAN + NGEMM) {
        gemm_body(ring0, w1ib, bb1, xw, gflags, bid - NSCAN, smem);
    } else {
        scan_body<1>(w1hb, xw, c0 + BATCH * HDIM, hA1, ring1,
                     hn + BATCH * HDIM, cn + BATCH * HDIM,
                     gflags, bid - NSCAN - NGEMM, smem);
    }
}

// ---------------- decode + log_softmax ----------------
__global__ __launch_bounds__(256)
void k_decode(const float* __restrict__ h1,
              const float* __restrict__ wdec,
              const float* __restrict__ bdec,
              float* __restrict__ out)
{
    __shared__ float hs[HDIM];
    __shared__ float ls[NINPUT];
    __shared__ float red[256];
    const int r = blockIdx.x, tid = threadIdx.x;
    reinterpret_cast<float4*>(hs)[tid] = reinterpret_cast<const float4*>(h1 + (size_t)r * HDIM)[tid];
    __syncthreads();
#pragma unroll
    for (int rep = 0; rep < 2; rep++) {
        int n = tid + rep * 256;
        float s = bdec[n];
        const float4* w4 = reinterpret_cast<const float4*>(wdec + (size_t)n * HDIM);
        for (int k = 0; k < HDIM / 4; k++) {
            float4 w = w4[k];
            float4 h4 = reinterpret_cast<const float4*>(hs)[k];
            s += w.x * h4.x + w.y * h4.y + w.z * h4.z + w.w * h4.w;
        }
        ls[n] = s;
    }
    __syncthreads();
    red[tid] = fmaxf(ls[tid], ls[tid + 256]);
    __syncthreads();
    for (int s2 = 128; s2 > 0; s2 >>= 1) {
        if (tid < s2) red[tid] = fmaxf(red[tid], red[tid + s2]);
        __syncthreads();
    }
    float M = red[0];
    __syncthreads();
    red[tid] = __expf(ls[tid] - M) + __expf(ls[tid + 256] - M);
    __syncthreads();
    for (int s2 = 128; s2 > 0; s2 >>= 1) {
        if (tid < s2) red[tid] += red[tid + s2];
        __syncthreads();
    }
    float lse = M + __logf(red[0]);
    out[(size_t)r * NINPUT + tid] = ls[tid] - lse;
    out[(size_t)r * NINPUT + tid + 256] = ls[tid + 256] - lse;
}

// ---------------- host launcher ----------------
extern "C" void kernel_launch(void* const* d_in, const int* in_sizes, int n_in,
                              void* d_out, int out_size, void* d_ws, size_t ws_size,
                              hipStream_t stream)
{
    const float* x    = (const float*)d_in[0];
    const float* h0   = (const float*)d_in[1];
    const float* c0   = (const float*)d_in[2];
    const float* wih0 = (const float*)d_in[3];
    const float* whh0 = (const float*)d_in[4];
    const float* bih0 = (const float*)d_in[5];
    const float* bhh0 = (const float*)d_in[6];
    const float* wih1 = (const float*)d_in[7];
    const float* whh1 = (const float*)d_in[8];
    const float* bih1 = (const float*)d_in[9];
    const float* bhh1 = (const float*)d_in[10];
    const float* wdec = (const float*)d_in[11];
    const float* bdec = (const float*)d_in[12];
    float* out = (float*)d_out;

    char* ws = (char*)d_ws;
    size_t off = 0;
    auto alloc = [&](size_t bytes) -> void* {
        void* p = ws + off;
        off += (bytes + 255) & ~(size_t)255;
        return p;
    };
    const size_t ring_bytes = (size_t)TSTEPS * BATCH * HDIM * 2;   // 33.5 MB

    unsigned short* xw    = (unsigned short*)alloc((size_t)BATCH * TSTEPS * G4 * 2);   // 134.2 MB time-major
    unsigned short* ring0 = (unsigned short*)alloc(ring_bytes);                        // 33.5 MB time-major
    unsigned short* w0hb  = (unsigned short*)alloc((size_t)G4 * HDIM * 2);
    unsigned short* w1ib  = (unsigned short*)alloc((size_t)G4 * HDIM * 2);
    unsigned short* w1hb  = (unsigned short*)alloc((size_t)G4 * HDIM * 2);
    float*          bb0   = (float*)alloc(G4 * 4);
    float*          bb1   = (float*)alloc(G4 * 4);
    unsigned short* hA0   = (unsigned short*)alloc(BATCH * HDIM * 2);
    unsigned short* hA1   = (unsigned short*)alloc(BATCH * HDIM * 2);
    unsigned*       gflags = (unsigned*)alloc(128 * 32 * 4);
    // ring1 overlays xb + w0ib (dead after gemm0) + explicit pad
    unsigned short* xb    = (unsigned short*)alloc((size_t)TSTEPS * BATCH * NINPUT * 2); // 16.8 MB
    unsigned short* w0ib  = (unsigned short*)alloc((size_t)G4 * NINPUT * 2);             // 4.2 MB
    unsigned short* ring1 = xb;
    {
        size_t have = (size_t)TSTEPS * BATCH * NINPUT * 2 + (size_t)G4 * NINPUT * 2;
        if (ring_bytes > have) alloc(ring_bytes - have);                                 // 12.6 MB pad
    }

    const long ring_n4 = (long)ring_bytes / 16;

    // replay safety: re-poison ring0, clear gflags (ring1 poisoned after gemm0)
    k_poison<<<2048, 256, 0, stream>>>((u32x4*)ring0, ring_n4);
    hipMemsetAsync(gflags, 0, 128 * 32 * 4, stream);

    k_f2b_tm<<<1024, 256, 0, stream>>>(x, xb);
    k_f2b<<<512, 256, 0, stream>>>(wih0, w0ib, (long)G4 * NINPUT);
    k_f2b<<<1024, 256, 0, stream>>>(whh0, w0hb, (long)G4 * HDIM);
    k_f2b<<<1024, 256, 0, stream>>>(wih1, w1ib, (long)G4 * HDIM);
    k_f2b<<<1024, 256, 0, stream>>>(whh1, w1hb, (long)G4 * HDIM);
    k_prep_small<<<512, 256, 0, stream>>>(bih0, bhh0, bih1, bhh1, bb0, bb1, h0, hA0, hA1);

    const int M = BATCH * TSTEPS;
    // layer 0 input projection (time-major rows): xw0 = xb @ wih0^T + (bih0+bhh0)
    k_gemm_bt<<<(M / BM) * (G4 / BN), 256, 0, stream>>>(xb, w0ib, bb0, xw, M, G4, NINPUT);

    // xb/w0ib now dead -> poison ring1 (full-T sentinel ring for scan1)
    k_poison<<<2048, 256, 0, stream>>>((u32x4*)ring1, ring_n4);

    // fused pipeline: scan0 | gemm1 (xw overwritten in place) | scan1
    k_fused<<<NSCAN + NGEMM + NSCAN, 256, 0, stream>>>(
        w0hb, w1hb, w1ib, bb1, xw, ring0, ring1, c0, hA0, hA1,
        out + 32768,
        out + 32768 + 2 * BATCH * HDIM,
        gflags);

    // decode from fp32 final h of layer 1
    k_decode<<<BATCH, 256, 0, stream>>>(out + 32768 + BATCH * HDIM, wdec, bdec, out);
}

// Round 12
// 2757.313 us; speedup vs baseline: 1.0558x; 1.0558x over previous
//
#include <hip/hip_runtime.h>

#define BATCH   64
#define TSTEPS  256
#define NINPUT  512
#define HDIM    1024
#define G4      4096   // 4*HDIM
#define NSCAN   64     // scan WGs per layer
#define NHC     16     // h-columns per scan WG
#define NGEMM   128    // persistent gemm WGs

typedef __attribute__((ext_vector_type(8))) short short8;
typedef __attribute__((ext_vector_type(4))) float f32x4;
typedef __attribute__((ext_vector_type(4))) unsigned int u32x4;
typedef __attribute__((ext_vector_type(2))) unsigned int u32x2;

static __device__ __forceinline__ unsigned short f2bf(float x) {
    unsigned u = __float_as_uint(x);
    unsigned r = 0x7fffu + ((u >> 16) & 1u);
    return (unsigned short)((u + r) >> 16);
}
static __device__ __forceinline__ float bf2f(unsigned short b) {
    return __uint_as_float(((unsigned)b) << 16);
}
static __device__ __forceinline__ float sigf(float x) {
    return 1.f / (1.f + __expf(-x));
}
static __device__ __forceinline__ float tanhf_fast(float x) {
    return 2.f / (1.f + __expf(-2.f * x)) - 1.f;
}

// ---------------- poison ring with bf16-NaN sentinel ----------------
__global__ void k_poison(u32x4* __restrict__ p, long n4) {
    long i = (long)blockIdx.x * blockDim.x + threadIdx.x;
    long st = (long)gridDim.x * blockDim.x;
    u32x4 v = (u32x4){0xFFFFFFFFu, 0xFFFFFFFFu, 0xFFFFFFFFu, 0xFFFFFFFFu};
    for (; i < n4; i += st) p[i] = v;
}

// ---------------- ALL prologue prep in one launch ----------------
// x->xb (time-major), 4 weight conversions, bias combines, h0 conversion,
// ring0 poison, gflags clear.
__global__ void k_prep_all(const float* __restrict__ x,    unsigned short* __restrict__ xb,
                           const float* __restrict__ wih0, unsigned short* __restrict__ w0ib,
                           const float* __restrict__ whh0, unsigned short* __restrict__ w0hb,
                           const float* __restrict__ wih1, unsigned short* __restrict__ w1ib,
                           const float* __restrict__ whh1, unsigned short* __restrict__ w1hb,
                           const float* __restrict__ bih0, const float* __restrict__ bhh0,
                           float* __restrict__ bb0,
                           const float* __restrict__ bih1, const float* __restrict__ bhh1,
                           float* __restrict__ bb1,
                           const float* __restrict__ h0,
                           unsigned short* __restrict__ hA0, unsigned short* __restrict__ hA1,
                           u32x4* __restrict__ ring0p, unsigned* __restrict__ gflags)
{
    const long tid0 = (long)blockIdx.x * blockDim.x + threadIdx.x;
    const long nthr = (long)gridDim.x * blockDim.x;

    // x -> xb with [B][T] -> [T][B] transpose (float4 granularity)
    {
        const long total4 = (long)BATCH * TSTEPS * NINPUT / 4;
        for (long i = tid0; i < total4; i += nthr) {
            long v = i * 4;
            long row = v / NINPUT;
            int ii = (int)(v - row * NINPUT);
            int b = (int)(row / TSTEPS);
            int t = (int)(row - (long)b * TSTEPS);
            float4 f = *reinterpret_cast<const float4*>(x + v);
            ushort4 o;
            o.x = f2bf(f.x); o.y = f2bf(f.y); o.z = f2bf(f.z); o.w = f2bf(f.w);
            *reinterpret_cast<ushort4*>(xb + ((size_t)t * BATCH + b) * NINPUT + ii) = o;
        }
    }
    // weight conversions (linear)
#define CVT(SRC, DST, N) { \
        const long n4 = (long)(N) / 4; \
        for (long i = tid0; i < n4; i += nthr) { \
            float4 f = *reinterpret_cast<const float4*>((SRC) + i * 4); \
            ushort4 o; \
            o.x = f2bf(f.x); o.y = f2bf(f.y); o.z = f2bf(f.z); o.w = f2bf(f.w); \
            *reinterpret_cast<ushort4*>((DST) + i * 4) = o; \
        } }
    CVT(wih0, w0ib, (long)G4 * NINPUT)
    CVT(whh0, w0hb, (long)G4 * HDIM)
    CVT(wih1, w1ib, (long)G4 * HDIM)
    CVT(whh1, w1hb, (long)G4 * HDIM)
#undef CVT
    // biases
    for (long i = tid0; i < G4; i += nthr) {
        bb0[i] = bih0[i] + bhh0[i];
        bb1[i] = bih1[i] + bhh1[i];
    }
    // h0 -> bf16 (both layers)
    for (long i = tid0; i < BATCH * HDIM; i += nthr) {
        hA0[i] = f2bf(h0[i]);
        hA1[i] = f2bf(h0[BATCH * HDIM + i]);
    }
    // ring0 poison
    {
        const long n4 = (long)TSTEPS * BATCH * HDIM * 2 / 16;
        u32x4 v = (u32x4){0xFFFFFFFFu, 0xFFFFFFFFu, 0xFFFFFFFFu, 0xFFFFFFFFu};
        for (long i = tid0; i < n4; i += nthr) ring0p[i] = v;
    }
    // gflags clear
    for (long i = tid0; i < 128 * 32; i += nthr) gflags[i] = 0;
}

// ---------------- standalone bf16 GEMM (layer-0 input projection) ----------------
#define BM 128
#define BN 128
#define BK 64

static __device__ __forceinline__ void g2l16(const unsigned short* g, void* lds) {
    __builtin_amdgcn_global_load_lds(
        (const __attribute__((address_space(1))) unsigned int*)g,
        (__attribute__((address_space(3))) unsigned int*)lds, 16, 0, 0);
}

__global__ __launch_bounds__(256)
void k_gemm_bt(const unsigned short* __restrict__ A,
               const unsigned short* __restrict__ B,
               const float* __restrict__ bias,
               unsigned short* __restrict__ C,
               int M, int N, int K)
{
    __shared__ unsigned short As[BM * BK];
    __shared__ unsigned short Bs[BN * BK];
    const int tid = threadIdx.x;
    const int lane = tid & 63, wv = tid >> 6;
    const int nbn = N / BN;
    const int bm0 = (blockIdx.x / nbn) * BM;
    const int bn0 = (blockIdx.x % nbn) * BN;
    const int wr = wv >> 1, wc = wv & 1;

    f32x4 acc[4][4];
#pragma unroll
    for (int i = 0; i < 4; i++)
#pragma unroll
        for (int j = 0; j < 4; j++) acc[i][j] = (f32x4){0.f, 0.f, 0.f, 0.f};

    const int srow = tid >> 3;
    const int scb  = (tid & 7) * 16;

    for (int kt = 0; kt < K; kt += BK) {
        __syncthreads();
#pragma unroll
        for (int is = 0; is < 4; is++) {
            int row = is * 32 + srow;
            int kb = scb ^ ((row & 7) << 4);
            g2l16(A + (size_t)(bm0 + row) * K + kt + (kb >> 1),
                  (char*)As + is * 4096 + wv * 1024);
        }
#pragma unroll
        for (int is = 0; is < 4; is++) {
            int row = is * 32 + srow;
            int kb = scb ^ ((row & 7) << 4);
            g2l16(B + (size_t)(bn0 + row) * K + kt + (kb >> 1),
                  (char*)Bs + is * 4096 + wv * 1024);
        }
        asm volatile("s_waitcnt vmcnt(0)" ::: "memory");
        __syncthreads();

#pragma unroll
        for (int ks = 0; ks < 2; ks++) {
            short8 a[4], b[4];
            const int kb = ks * 64 + ((lane >> 4) << 4);
#pragma unroll
            for (int mt = 0; mt < 4; mt++) {
                int r = wr * 64 + mt * 16 + (lane & 15);
                a[mt] = *reinterpret_cast<const short8*>(
                    (const char*)As + r * 128 + (kb ^ ((r & 7) << 4)));
            }
#pragma unroll
            for (int nt = 0; nt < 4; nt++) {
                int n = wc * 64 + nt * 16 + (lane & 15);
                b[nt] = *reinterpret_cast<const short8*>(
                    (const char*)Bs + n * 128 + (kb ^ ((n & 7) << 4)));
            }
#pragma unroll
            for (int mt = 0; mt < 4; mt++)
#pragma unroll
                for (int nt = 0; nt < 4; nt++)
                    acc[mt][nt] = __builtin_amdgcn_mfma_f32_16x16x32_bf16(
                        a[mt], b[nt], acc[mt][nt], 0, 0, 0);
        }
    }

#pragma unroll
    for (int nt = 0; nt < 4; nt++) {
        int cg = bn0 + wc * 64 + nt * 16 + (lane & 15);
        float bv = bias[cg];
#pragma unroll
        for (int mt = 0; mt < 4; mt++) {
#pragma unroll
            for (int e = 0; e < 4; e++) {
                int rg = bm0 + wr * 64 + mt * 16 + ((lane >> 4) << 2) + e;
                C[(size_t)rg * N + cg] = f2bf(acc[mt][nt][e] + bv);
            }
        }
    }
}

// =====================================================================
// Fused pipeline: scan0 (WG 0-63) | gemm1 (WG 64-191) | scan1 (WG 192-255)
// Time-major: xw rows = t*64+b; ring slot t = [64][1024] bf16 contiguous.
// Both scans: full-T sentinel rings, direct full-load retry (r10 proven).
// =====================================================================

template<int L>
static __device__ void scan_body(const unsigned short* __restrict__ whh,
                                 const unsigned short* __restrict__ xw,
                                 const float* __restrict__ c0,
                                 const unsigned short* __restrict__ h0b,
                                 unsigned short* __restrict__ ring,   // [T][64][1024] bf16, poisoned
                                 float* __restrict__ hn, float* __restrict__ cn,
                                 const unsigned* __restrict__ gflags,
                                 int wg, char* smem)
{
    float (*plds)[64][34] = reinterpret_cast<float (*)[64][34]>(smem);
    const int tid = threadIdx.x;
    const int lane = tid & 63, kw = tid >> 6;
    const int colbase = wg * NHC;
    const int cb = wg >> 3;     // n-tile sub-index for gemm flags

    short8 bfr[4][8];
    {
        const int c = lane & 15;
#pragma unroll
        for (int g = 0; g < 4; g++) {
            int grow = g * HDIM + colbase + c;
#pragma unroll
            for (int s = 0; s < 8; s++) {
                int k = kw * 256 + s * 32 + ((lane >> 4) << 3);
                bfr[g][s] = *reinterpret_cast<const short8*>(whh + (size_t)grow * HDIM + k);
            }
        }
    }

    const int r2 = tid >> 2;
    const int u0 = (tid & 3) * 4;
    f32x4 cst = *reinterpret_cast<const f32x4*>(c0 + (size_t)r2 * HDIM + colbase + u0);

    const int arow = lane & 15;
    const size_t koff = (size_t)kw * 256 + ((lane >> 4) << 3);
    int wm = 0;   // L==1: gemm m-tiles complete through wm-1

    for (int t = 0; t < TSTEPS; t++) {
        // ---- xw for this step ----
        const unsigned short* xp = xw + ((size_t)t * BATCH + r2) * G4 + colbase + u0;
        u32x2 xi, xf, xg, xo;
        if (L == 0) {
            xi = *reinterpret_cast<const u32x2*>(xp);
            xf = *reinterpret_cast<const u32x2*>(xp + HDIM);
            xg = *reinterpret_cast<const u32x2*>(xp + 2 * HDIM);
            xo = *reinterpret_cast<const u32x2*>(xp + 3 * HDIM);
        } else {
            const int mt = t >> 1;
            while (mt >= wm) {
                int mti = wm + (lane >> 2); if (mti > 127) mti = 127;
                const unsigned* fp = gflags + mti * 32 + (lane & 3) * 8 + cb;
                unsigned v;
                asm volatile("global_load_dword %0, %1, off sc0 sc1" : "=v"(v) : "v"(fp));
                asm volatile("s_waitcnt vmcnt(0)" ::: "memory");
                __builtin_amdgcn_sched_barrier(0);
                unsigned long long mk = __ballot(v != 0);
                int adv = 0;
                while (adv < 16 && ((mk >> (4 * adv)) & 0xFull) == 0xFull) adv++;
                wm += adv;
                if (adv == 0) __builtin_amdgcn_s_sleep(16);
            }
            asm volatile("global_load_dwordx2 %0, %1, off sc0 sc1" : "=v"(xi) : "v"(xp));
            asm volatile("global_load_dwordx2 %0, %1, off sc0 sc1" : "=v"(xf) : "v"(xp + HDIM));
            asm volatile("global_load_dwordx2 %0, %1, off sc0 sc1" : "=v"(xg) : "v"(xp + 2 * HDIM));
            asm volatile("global_load_dwordx2 %0, %1, off sc0 sc1" : "=v"(xo) : "v"(xp + 3 * HDIM));
        }

        // ---- h(t-1) fragment base ----
        const unsigned short* pa0;
        if (t == 0) pa0 = h0b + (size_t)arow * HDIM + koff;
        else        pa0 = ring + ((size_t)(t - 1) * BATCH + arow) * HDIM + koff;
        const unsigned short* pa1 = pa0 + 16 * HDIM;
        const unsigned short* pa2 = pa0 + 32 * HDIM;
        const unsigned short* pa3 = pa0 + 48 * HDIM;

        // ---- load + sentinel-validate, direct retry (r10 proven) ----
        u32x4 afr[8][4];
#define ISSUE4(S, OFFS) \
        asm volatile("global_load_dwordx4 %0, %1, off offset:" OFFS " sc0 sc1" : "=v"(afr[S][0]) : "v"(pa0)); \
        asm volatile("global_load_dwordx4 %0, %1, off offset:" OFFS " sc0 sc1" : "=v"(afr[S][1]) : "v"(pa1)); \
        asm volatile("global_load_dwordx4 %0, %1, off offset:" OFFS " sc0 sc1" : "=v"(afr[S][2]) : "v"(pa2)); \
        asm volatile("global_load_dwordx4 %0, %1, off offset:" OFFS " sc0 sc1" : "=v"(afr[S][3]) : "v"(pa3));
        for (;;) {
            ISSUE4(0, "0")   ISSUE4(1, "64")  ISSUE4(2, "128") ISSUE4(3, "192")
            ISSUE4(4, "256") ISSUE4(5, "320") ISSUE4(6, "384") ISSUE4(7, "448")
            asm volatile("s_waitcnt vmcnt(0)" ::: "memory");
            __builtin_amdgcn_sched_barrier(0);
            unsigned mx = 0;
#pragma unroll
            for (int s = 0; s < 8; s++)
#pragma unroll
                for (int m = 0; m < 4; m++) {
                    u32x4 u = afr[s][m];
                    unsigned a = u[0] > u[1] ? u[0] : u[1];
                    unsigned b = u[2] > u[3] ? u[2] : u[3];
                    unsigned c = a > b ? a : b;
                    mx = mx > c ? mx : c;
                }
            if (!__any(mx >= 0xFFFF0000u)) break;
            __builtin_amdgcn_s_sleep(1);
        }
#undef ISSUE4

        // ---- MFMA ----
        f32x4 acc[4][4];
#pragma unroll
        for (int m = 0; m < 4; m++)
#pragma unroll
            for (int g = 0; g < 4; g++) acc[m][g] = (f32x4){0.f, 0.f, 0.f, 0.f};
#pragma unroll
        for (int s = 0; s < 8; s++)
#pragma unroll
            for (int m = 0; m < 4; m++) {
                short8 av = __builtin_bit_cast(short8, afr[s][m]);
#pragma unroll
                for (int g = 0; g < 4; g++)
                    acc[m][g] = __builtin_amdgcn_mfma_f32_16x16x32_bf16(
                        av, bfr[g][s], acc[m][g], 0, 0, 0);
            }

        // ---- pass A (gates i,f) ----
#pragma unroll
        for (int m = 0; m < 4; m++)
#pragma unroll
            for (int g = 0; g < 2; g++) {
                int col = g * 16 + (lane & 15);
                int rb = m * 16 + ((lane >> 4) << 2);
#pragma unroll
                for (int e = 0; e < 4; e++)
                    plds[kw][rb + e][col] = acc[m][g][e];
            }
        __syncthreads();
        f32x4 sI = (f32x4){0.f,0.f,0.f,0.f}, sF = sI;
#pragma unroll
        for (int w = 0; w < 4; w++) {
            sI += *reinterpret_cast<const f32x4*>(&plds[w][r2][u0]);
            sF += *reinterpret_cast<const f32x4*>(&plds[w][r2][16 + u0]);
        }
        __syncthreads();
        // ---- pass B (gates g,o) ----
#pragma unroll
        for (int m = 0; m < 4; m++)
#pragma unroll
            for (int g = 2; g < 4; g++) {
                int col = (g - 2) * 16 + (lane & 15);
                int rb = m * 16 + ((lane >> 4) << 2);
#pragma unroll
                for (int e = 0; e < 4; e++)
                    plds[kw][rb + e][col] = acc[m][g][e];
            }
        __syncthreads();
        f32x4 sG = (f32x4){0.f,0.f,0.f,0.f}, sO = sG;
#pragma unroll
        for (int w = 0; w < 4; w++) {
            sG += *reinterpret_cast<const f32x4*>(&plds[w][r2][u0]);
            sO += *reinterpret_cast<const f32x4*>(&plds[w][r2][16 + u0]);
        }
        __syncthreads();

#define ADDX(S, V) { unsigned lo = V[0], hi = V[1]; \
        S[0] += bf2f((unsigned short)lo); S[1] += bf2f((unsigned short)(lo >> 16)); \
        S[2] += bf2f((unsigned short)hi); S[3] += bf2f((unsigned short)(hi >> 16)); }
        ADDX(sI, xi) ADDX(sF, xf) ADDX(sG, xg) ADDX(sO, xo)
#undef ADDX

        float hv[4];
#pragma unroll
        for (int j = 0; j < 4; j++) {
            float c = sigf(sF[j]) * cst[j] + sigf(sI[j]) * tanhf_fast(sG[j]);
            cst[j] = c;
            hv[j] = sigf(sO[j]) * tanhf_fast(c);
        }
        u32x2 hp;
        hp[0] = (unsigned)f2bf(hv[0]) | ((unsigned)f2bf(hv[1]) << 16);
        hp[1] = (unsigned)f2bf(hv[2]) | ((unsigned)f2bf(hv[3]) << 16);
        unsigned short* wp = ring + ((size_t)t * BATCH + r2) * HDIM + colbase + u0;
        asm volatile("global_store_dwordx2 %0, %1, off sc0 sc1"
                     :: "v"(wp), "v"(hp) : "memory");

        if (t == TSTEPS - 1) {
            const size_t hi_ = (size_t)r2 * HDIM + colbase + u0;
            *reinterpret_cast<f32x4*>(hn + hi_) = (f32x4){hv[0], hv[1], hv[2], hv[3]};
            *reinterpret_cast<f32x4*>(cn + hi_) = cst;
        }
    }
}

// ---- persistent gemm body: xw1 = ring0 @ w1ib^T + bb1, t-ordered jobs, flags ----
static __device__ void gemm_body(const unsigned short* __restrict__ A,    // ring0
                                 const unsigned short* __restrict__ B,    // w1ib
                                 const float* __restrict__ bias,
                                 unsigned short* __restrict__ C,          // xw (in-place)
                                 unsigned* __restrict__ gflags,
                                 int gw, char* smem)
{
    unsigned short* As = reinterpret_cast<unsigned short*>(smem);
    unsigned short* Bs = As + BM * BK;
    const int tid = threadIdx.x;
    const int lane = tid & 63, wv = tid >> 6;
    const int wr = wv >> 1, wc = wv & 1;
    const int srow = tid >> 3;
    const int scb  = (tid & 7) * 16;

    for (int i = 0; i < 32; i++) {
        const int j = i * NGEMM + gw;
        const int mt = j >> 5;
        const int nt = j & 31;
        const int bm0 = mt * BM, bn0 = nt * BN;

        {
            const unsigned short* lr = A + ((size_t)bm0 + 127) * HDIM + lane * 16;
            for (;;) {
                unsigned v;
                asm volatile("global_load_dword %0, %1, off sc0 sc1" : "=v"(v) : "v"(lr));
                asm volatile("s_waitcnt vmcnt(0)" ::: "memory");
                __builtin_amdgcn_sched_barrier(0);
                if (!__any(v >= 0xFFFF0000u)) break;
                __builtin_amdgcn_s_sleep(16);
            }
        }

        f32x4 acc[4][4];
#pragma unroll
        for (int a = 0; a < 4; a++)
#pragma unroll
            for (int b = 0; b < 4; b++) acc[a][b] = (f32x4){0.f, 0.f, 0.f, 0.f};

        for (int kt = 0; kt < HDIM; kt += BK) {
            __syncthreads();
#pragma unroll
            for (int is = 0; is < 4; is++) {
                int row = is * 32 + srow;
                int kb = scb ^ ((row & 7) << 4);
                g2l16(B + (size_t)(bn0 + row) * HDIM + kt + (kb >> 1),
                      (char*)Bs + is * 4096 + wv * 1024);
            }
            const unsigned short* ap[4];
#pragma unroll
            for (int is = 0; is < 4; is++) {
                int row = is * 32 + srow;
                int kb = scb ^ ((row & 7) << 4);
                ap[is] = A + (size_t)(bm0 + row) * HDIM + kt + (kb >> 1);
            }
            u32x4 av0, av1, av2, av3;
            for (;;) {
                asm volatile("global_load_dwordx4 %0, %1, off sc0 sc1" : "=v"(av0) : "v"(ap[0]));
                asm volatile("global_load_dwordx4 %0, %1, off sc0 sc1" : "=v"(av1) : "v"(ap[1]));
                asm volatile("global_load_dwordx4 %0, %1, off sc0 sc1" : "=v"(av2) : "v"(ap[2]));
                asm volatile("global_load_dwordx4 %0, %1, off sc0 sc1" : "=v"(av3) : "v"(ap[3]));
                asm volatile("s_waitcnt vmcnt(0)" ::: "memory");
                __builtin_amdgcn_sched_barrier(0);
                unsigned mx = 0;
#pragma unroll
                for (int e = 0; e < 4; e++) {
                    unsigned a01 = av0[e] > av1[e] ? av0[e] : av1[e];
                    unsigned a23 = av2[e] > av3[e] ? av2[e] : av3[e];
                    unsigned m = a01 > a23 ? a01 : a23;
                    mx = mx > m ? mx : m;
                }
                if (mx < 0xFFFF0000u) break;
                __builtin_amdgcn_s_sleep(2);
            }
            char* asb = (char*)As;
            *reinterpret_cast<u32x4*>(asb + 0 * 4096 + wv * 1024 + lane * 16) = av0;
            *reinterpret_cast<u32x4*>(asb + 1 * 4096 + wv * 1024 + lane * 16) = av1;
            *reinterpret_cast<u32x4*>(asb + 2 * 4096 + wv * 1024 + lane * 16) = av2;
            *reinterpret_cast<u32x4*>(asb + 3 * 4096 + wv * 1024 + lane * 16) = av3;
            __syncthreads();

#pragma unroll
            for (int ks = 0; ks < 2; ks++) {
                short8 a[4], b[4];
                const int kb = ks * 64 + ((lane >> 4) << 4);
#pragma unroll
                for (int m = 0; m < 4; m++) {
                    int r = wr * 64 + m * 16 + (lane & 15);
                    a[m] = *reinterpret_cast<const short8*>(
                        (const char*)As + r * 128 + (kb ^ ((r & 7) << 4)));
                }
#pragma unroll
                for (int n = 0; n < 4; n++) {
                    int nn = wc * 64 + n * 16 + (lane & 15);
                    b[n] = *reinterpret_cast<const short8*>(
                        (const char*)Bs + nn * 128 + (kb ^ ((nn & 7) << 4)));
                }
#pragma unroll
                for (int m = 0; m < 4; m++)
#pragma unroll
                    for (int n = 0; n < 4; n++)
                        acc[m][n] = __builtin_amdgcn_mfma_f32_16x16x32_bf16(
                            a[m], b[n], acc[m][n], 0, 0, 0);
            }
        }

#pragma unroll
        for (int n = 0; n < 4; n++) {
            int cg = bn0 + wc * 64 + n * 16 + (lane & 15);
            float bv = bias[cg];
#pragma unroll
            for (int m = 0; m < 4; m++) {
#pragma unroll
                for (int e = 0; e < 4; e++) {
                    int rg = bm0 + wr * 64 + m * 16 + ((lane >> 4) << 2) + e;
                    unsigned val = f2bf(acc[m][n][e] + bv);
                    const unsigned short* cp = C + (size_t)rg * G4 + cg;
                    asm volatile("global_store_short %0, %1, off sc0 sc1"
                                 :: "v"(cp), "v"(val) : "memory");
                }
            }
        }
        asm volatile("s_waitcnt vmcnt(0)" ::: "memory");
        __syncthreads();
        if (tid == 0) {
            unsigned one = 1;
            asm volatile("global_store_dword %0, %1, off sc0 sc1"
                         :: "v"(gflags + mt * 32 + nt), "v"(one) : "memory");
        }
    }
}

__global__ __launch_bounds__(256, 1)
void k_fused(const unsigned short* __restrict__ w0hb,
             const unsigned short* __restrict__ w1hb,
             const unsigned short* __restrict__ w1ib,
             const float* __restrict__ bb1,
             unsigned short* __restrict__ xw,
             unsigned short* __restrict__ ring0,
             unsigned short* __restrict__ ring1,
             const float* __restrict__ c0,
             const unsigned short* __restrict__ hA0,
             const unsigned short* __restrict__ hA1,
             float* __restrict__ hn, float* __restrict__ cn,
             unsigned* __restrict__ gflags)
{
    __shared__ alignas(16) char smem[4 * 64 * 34 * 4];
    const int bid = blockIdx.x;
    if (bid < NSCAN) {
        scan_body<0>(w0hb, xw, c0, hA0, ring0, hn, cn, nullptr, bid, smem);
    } else if (bid < NSCAN + NGEMM) {
        gemm_body(ring0, w1ib, bb1, xw, gflags, bid - NSCAN, smem);
    } else {
        scan_body<1>(w1hb, xw, c0 + BATCH * HDIM, hA1, ring1,
                     hn + BATCH * HDIM, cn + BATCH * HDIM,
                     gflags, bid - NSCAN - NGEMM, smem);
    }
}

// ---------------- decode + log_softmax ----------------
__global__ __launch_bounds__(256)
void k_decode(const float* __restrict__ h1,
              const float* __restrict__ wdec,
              const float* __restrict__ bdec,
              float* __restrict__ out)
{
    __shared__ float hs[HDIM];
    __shared__ float ls[NINPUT];
    __shared__ float red[256];
    const int r = blockIdx.x, tid = threadIdx.x;
    reinterpret_cast<float4*>(hs)[tid] = reinterpret_cast<const float4*>(h1 + (size_t)r * HDIM)[tid];
    __syncthreads();
#pragma unroll
    for (int rep = 0; rep < 2; rep++) {
        int n = tid + rep * 256;
        float s = bdec[n];
        const float4* w4 = reinterpret_cast<const float4*>(wdec + (size_t)n * HDIM);
        for (int k = 0; k < HDIM / 4; k++) {
            float4 w = w4[k];
            float4 h4 = reinterpret_cast<const float4*>(hs)[k];
            s += w.x * h4.x + w.y * h4.y + w.z * h4.z + w.w * h4.w;
        }
        ls[n] = s;
    }
    __syncthreads();
    red[tid] = fmaxf(ls[tid], ls[tid + 256]);
    __syncthreads();
    for (int s2 = 128; s2 > 0; s2 >>= 1) {
        if (tid < s2) red[tid] = fmaxf(red[tid], red[tid + s2]);
        __syncthreads();
    }
    float M = red[0];
    __syncthreads();
    red[tid] = __expf(ls[tid] - M) + __expf(ls[tid + 256] - M);
    __syncthreads();
    for (int s2 = 128; s2 > 0; s2 >>= 1) {
        if (tid < s2) red[tid] += red[tid + s2];
        __syncthreads();
    }
    float lse = M + __logf(red[0]);
    out[(size_t)r * NINPUT + tid] = ls[tid] - lse;
    out[(size_t)r * NINPUT + tid + 256] = ls[tid + 256] - lse;
}

// ---------------- host launcher ----------------
extern "C" void kernel_launch(void* const* d_in, const int* in_sizes, int n_in,
                              void* d_out, int out_size, void* d_ws, size_t ws_size,
                              hipStream_t stream)
{
    const float* x    = (const float*)d_in[0];
    const float* h0   = (const float*)d_in[1];
    const float* c0   = (const float*)d_in[2];
    const float* wih0 = (const float*)d_in[3];
    const float* whh0 = (const float*)d_in[4];
    const float* bih0 = (const float*)d_in[5];
    const float* bhh0 = (const float*)d_in[6];
    const float* wih1 = (const float*)d_in[7];
    const float* whh1 = (const float*)d_in[8];
    const float* bih1 = (const float*)d_in[9];
    const float* bhh1 = (const float*)d_in[10];
    const float* wdec = (const float*)d_in[11];
    const float* bdec = (const float*)d_in[12];
    float* out = (float*)d_out;

    char* ws = (char*)d_ws;
    size_t off = 0;
    auto alloc = [&](size_t bytes) -> void* {
        void* p = ws + off;
        off += (bytes + 255) & ~(size_t)255;
        return p;
    };
    const size_t ring_bytes = (size_t)TSTEPS * BATCH * HDIM * 2;   // 33.5 MB

    unsigned short* xw    = (unsigned short*)alloc((size_t)BATCH * TSTEPS * G4 * 2);   // 134.2 MB time-major
    unsigned short* ring0 = (unsigned short*)alloc(ring_bytes);                        // 33.5 MB time-major
    unsigned short* w0hb  = (unsigned short*)alloc((size_t)G4 * HDIM * 2);
    unsigned short* w1ib  = (unsigned short*)alloc((size_t)G4 * HDIM * 2);
    unsigned short* w1hb  = (unsigned short*)alloc((size_t)G4 * HDIM * 2);
    float*          bb0   = (float*)alloc(G4 * 4);
    float*          bb1   = (float*)alloc(G4 * 4);
    unsigned short* hA0   = (unsigned short*)alloc(BATCH * HDIM * 2);
    unsigned short* hA1   = (unsigned short*)alloc(BATCH * HDIM * 2);
    unsigned*       gflags = (unsigned*)alloc(128 * 32 * 4);
    // ring1 overlays xb + w0ib (dead after gemm0) + explicit pad
    unsigned short* xb    = (unsigned short*)alloc((size_t)TSTEPS * BATCH * NINPUT * 2); // 16.8 MB
    unsigned short* w0ib  = (unsigned short*)alloc((size_t)G4 * NINPUT * 2);             // 4.2 MB
    unsigned short* ring1 = xb;
    {
        size_t have = (size_t)TSTEPS * BATCH * NINPUT * 2 + (size_t)G4 * NINPUT * 2;
        if (ring_bytes > have) alloc(ring_bytes - have);                                 // 12.6 MB pad
    }

    const long ring_n4 = (long)ring_bytes / 16;

    // single prologue kernel: conversions + biases + h0 + ring0 poison + gflags clear
    k_prep_all<<<2048, 256, 0, stream>>>(x, xb, wih0, w0ib, whh0, w0hb,
                                         wih1, w1ib, whh1, w1hb,
                                         bih0, bhh0, bb0, bih1, bhh1, bb1,
                                         h0, hA0, hA1, (u32x4*)ring0, gflags);

    const int M = BATCH * TSTEPS;
    // layer 0 input projection (time-major rows): xw0 = xb @ wih0^T + (bih0+bhh0)
    k_gemm_bt<<<(M / BM) * (G4 / BN), 256, 0, stream>>>(xb, w0ib, bb0, xw, M, G4, NINPUT);

    // xb/w0ib now dead -> poison ring1 (full-T sentinel ring for scan1)
    k_poison<<<2048, 256, 0, stream>>>((u32x4*)ring1, ring_n4);

    // fused pipeline: scan0 | gemm1 (xw overwritten in place) | scan1
    k_fused<<<NSCAN + NGEMM + NSCAN, 256, 0, stream>>>(
        w0hb, w1hb, w1ib, bb1, xw, ring0, ring1, c0, hA0, hA1,
        out + 32768,
        out + 32768 + 2 * BATCH * HDIM,
        gflags);

    // decode from fp32 final h of layer 1
    k_decode<<<BATCH, 256, 0, stream>>>(out + 32768 + BATCH * HDIM, wdec, bdec, out);
}

// Round 13
// 2723.705 us; speedup vs baseline: 1.0688x; 1.0123x over previous
//
#include <hip/hip_runtime.h>

#define BATCH   64
#define TSTEPS  256
#define NINPUT  512
#define HDIM    1024
#define G4      4096   // 4*HDIM
#define NSCAN   64     // scan WGs per layer
#define NHC     16     // h-columns per scan WG
#define NGEMM   32     // persistent gemm WGs (r13: 128->32, interference test)

typedef __attribute__((ext_vector_type(8))) short short8;
typedef __attribute__((ext_vector_type(4))) float f32x4;
typedef __attribute__((ext_vector_type(4))) unsigned int u32x4;
typedef __attribute__((ext_vector_type(2))) unsigned int u32x2;

static __device__ __forceinline__ unsigned short f2bf(float x) {
    unsigned u = __float_as_uint(x);
    unsigned r = 0x7fffu + ((u >> 16) & 1u);
    return (unsigned short)((u + r) >> 16);
}
static __device__ __forceinline__ float bf2f(unsigned short b) {
    return __uint_as_float(((unsigned)b) << 16);
}
static __device__ __forceinline__ float sigf(float x) {
    return 1.f / (1.f + __expf(-x));
}
static __device__ __forceinline__ float tanhf_fast(float x) {
    return 2.f / (1.f + __expf(-2.f * x)) - 1.f;
}

// ---------------- poison ring with bf16-NaN sentinel ----------------
__global__ void k_poison(u32x4* __restrict__ p, long n4) {
    long i = (long)blockIdx.x * blockDim.x + threadIdx.x;
    long st = (long)gridDim.x * blockDim.x;
    u32x4 v = (u32x4){0xFFFFFFFFu, 0xFFFFFFFFu, 0xFFFFFFFFu, 0xFFFFFFFFu};
    for (; i < n4; i += st) p[i] = v;
}

// ---------------- ALL prologue prep in one launch ----------------
__global__ void k_prep_all(const float* __restrict__ x,    unsigned short* __restrict__ xb,
                           const float* __restrict__ wih0, unsigned short* __restrict__ w0ib,
                           const float* __restrict__ whh0, unsigned short* __restrict__ w0hb,
                           const float* __restrict__ wih1, unsigned short* __restrict__ w1ib,
                           const float* __restrict__ whh1, unsigned short* __restrict__ w1hb,
                           const float* __restrict__ bih0, const float* __restrict__ bhh0,
                           float* __restrict__ bb0,
                           const float* __restrict__ bih1, const float* __restrict__ bhh1,
                           float* __restrict__ bb1,
                           const float* __restrict__ h0,
                           unsigned short* __restrict__ hA0, unsigned short* __restrict__ hA1,
                           u32x4* __restrict__ ring0p, unsigned* __restrict__ gflags)
{
    const long tid0 = (long)blockIdx.x * blockDim.x + threadIdx.x;
    const long nthr = (long)gridDim.x * blockDim.x;

    // x -> xb with [B][T] -> [T][B] transpose (float4 granularity)
    {
        const long total4 = (long)BATCH * TSTEPS * NINPUT / 4;
        for (long i = tid0; i < total4; i += nthr) {
            long v = i * 4;
            long row = v / NINPUT;
            int ii = (int)(v - row * NINPUT);
            int b = (int)(row / TSTEPS);
            int t = (int)(row - (long)b * TSTEPS);
            float4 f = *reinterpret_cast<const float4*>(x + v);
            ushort4 o;
            o.x = f2bf(f.x); o.y = f2bf(f.y); o.z = f2bf(f.z); o.w = f2bf(f.w);
            *reinterpret_cast<ushort4*>(xb + ((size_t)t * BATCH + b) * NINPUT + ii) = o;
        }
    }
#define CVT(SRC, DST, N) { \
        const long n4 = (long)(N) / 4; \
        for (long i = tid0; i < n4; i += nthr) { \
            float4 f = *reinterpret_cast<const float4*>((SRC) + i * 4); \
            ushort4 o; \
            o.x = f2bf(f.x); o.y = f2bf(f.y); o.z = f2bf(f.z); o.w = f2bf(f.w); \
            *reinterpret_cast<ushort4*>((DST) + i * 4) = o; \
        } }
    CVT(wih0, w0ib, (long)G4 * NINPUT)
    CVT(whh0, w0hb, (long)G4 * HDIM)
    CVT(wih1, w1ib, (long)G4 * HDIM)
    CVT(whh1, w1hb, (long)G4 * HDIM)
#undef CVT
    for (long i = tid0; i < G4; i += nthr) {
        bb0[i] = bih0[i] + bhh0[i];
        bb1[i] = bih1[i] + bhh1[i];
    }
    for (long i = tid0; i < BATCH * HDIM; i += nthr) {
        hA0[i] = f2bf(h0[i]);
        hA1[i] = f2bf(h0[BATCH * HDIM + i]);
    }
    {
        const long n4 = (long)TSTEPS * BATCH * HDIM * 2 / 16;
        u32x4 v = (u32x4){0xFFFFFFFFu, 0xFFFFFFFFu, 0xFFFFFFFFu, 0xFFFFFFFFu};
        for (long i = tid0; i < n4; i += nthr) ring0p[i] = v;
    }
    for (long i = tid0; i < 128 * 32; i += nthr) gflags[i] = 0;
}

// ---------------- standalone bf16 GEMM (layer-0 input projection) ----------------
#define BM 128
#define BN 128
#define BK 64

static __device__ __forceinline__ void g2l16(const unsigned short* g, void* lds) {
    __builtin_amdgcn_global_load_lds(
        (const __attribute__((address_space(1))) unsigned int*)g,
        (__attribute__((address_space(3))) unsigned int*)lds, 16, 0, 0);
}

__global__ __launch_bounds__(256)
void k_gemm_bt(const unsigned short* __restrict__ A,
               const unsigned short* __restrict__ B,
               const float* __restrict__ bias,
               unsigned short* __restrict__ C,
               int M, int N, int K)
{
    __shared__ unsigned short As[BM * BK];
    __shared__ unsigned short Bs[BN * BK];
    const int tid = threadIdx.x;
    const int lane = tid & 63, wv = tid >> 6;
    const int nbn = N / BN;
    const int bm0 = (blockIdx.x / nbn) * BM;
    const int bn0 = (blockIdx.x % nbn) * BN;
    const int wr = wv >> 1, wc = wv & 1;

    f32x4 acc[4][4];
#pragma unroll
    for (int i = 0; i < 4; i++)
#pragma unroll
        for (int j = 0; j < 4; j++) acc[i][j] = (f32x4){0.f, 0.f, 0.f, 0.f};

    const int srow = tid >> 3;
    const int scb  = (tid & 7) * 16;

    for (int kt = 0; kt < K; kt += BK) {
        __syncthreads();
#pragma unroll
        for (int is = 0; is < 4; is++) {
            int row = is * 32 + srow;
            int kb = scb ^ ((row & 7) << 4);
            g2l16(A + (size_t)(bm0 + row) * K + kt + (kb >> 1),
                  (char*)As + is * 4096 + wv * 1024);
        }
#pragma unroll
        for (int is = 0; is < 4; is++) {
            int row = is * 32 + srow;
            int kb = scb ^ ((row & 7) << 4);
            g2l16(B + (size_t)(bn0 + row) * K + kt + (kb >> 1),
                  (char*)Bs + is * 4096 + wv * 1024);
        }
        asm volatile("s_waitcnt vmcnt(0)" ::: "memory");
        __syncthreads();

#pragma unroll
        for (int ks = 0; ks < 2; ks++) {
            short8 a[4], b[4];
            const int kb = ks * 64 + ((lane >> 4) << 4);
#pragma unroll
            for (int mt = 0; mt < 4; mt++) {
                int r = wr * 64 + mt * 16 + (lane & 15);
                a[mt] = *reinterpret_cast<const short8*>(
                    (const char*)As + r * 128 + (kb ^ ((r & 7) << 4)));
            }
#pragma unroll
            for (int nt = 0; nt < 4; nt++) {
                int n = wc * 64 + nt * 16 + (lane & 15);
                b[nt] = *reinterpret_cast<const short8*>(
                    (const char*)Bs + n * 128 + (kb ^ ((n & 7) << 4)));
            }
#pragma unroll
            for (int mt = 0; mt < 4; mt++)
#pragma unroll
                for (int nt = 0; nt < 4; nt++)
                    acc[mt][nt] = __builtin_amdgcn_mfma_f32_16x16x32_bf16(
                        a[mt], b[nt], acc[mt][nt], 0, 0, 0);
        }
    }

#pragma unroll
    for (int nt = 0; nt < 4; nt++) {
        int cg = bn0 + wc * 64 + nt * 16 + (lane & 15);
        float bv = bias[cg];
#pragma unroll
        for (int mt = 0; mt < 4; mt++) {
#pragma unroll
            for (int e = 0; e < 4; e++) {
                int rg = bm0 + wr * 64 + mt * 16 + ((lane >> 4) << 2) + e;
                C[(size_t)rg * N + cg] = f2bf(acc[mt][nt][e] + bv);
            }
        }
    }
}

// =====================================================================
// Fused pipeline: scan0 (WG 0-63) | gemm1 (WG 64-95) | scan1 (WG 96-159)
// Time-major: xw rows = t*64+b; ring slot t = [64][1024] bf16 contiguous.
// Both scans: full-T sentinel rings, direct full-load retry (r10 proven).
// =====================================================================

template<int L>
static __device__ void scan_body(const unsigned short* __restrict__ whh,
                                 const unsigned short* __restrict__ xw,
                                 const float* __restrict__ c0,
                                 const unsigned short* __restrict__ h0b,
                                 unsigned short* __restrict__ ring,   // [T][64][1024] bf16, poisoned
                                 float* __restrict__ hn, float* __restrict__ cn,
                                 const unsigned* __restrict__ gflags,
                                 int wg, char* smem)
{
    float (*plds)[64][34] = reinterpret_cast<float (*)[64][34]>(smem);
    const int tid = threadIdx.x;
    const int lane = tid & 63, kw = tid >> 6;
    const int colbase = wg * NHC;
    const int cb = wg >> 3;     // n-tile sub-index for gemm flags

    short8 bfr[4][8];
    {
        const int c = lane & 15;
#pragma unroll
        for (int g = 0; g < 4; g++) {
            int grow = g * HDIM + colbase + c;
#pragma unroll
            for (int s = 0; s < 8; s++) {
                int k = kw * 256 + s * 32 + ((lane >> 4) << 3);
                bfr[g][s] = *reinterpret_cast<const short8*>(whh + (size_t)grow * HDIM + k);
            }
        }
    }

    const int r2 = tid >> 2;
    const int u0 = (tid & 3) * 4;
    f32x4 cst = *reinterpret_cast<const f32x4*>(c0 + (size_t)r2 * HDIM + colbase + u0);

    const int arow = lane & 15;
    const size_t koff = (size_t)kw * 256 + ((lane >> 4) << 3);
    int wm = 0;   // L==1: gemm m-tiles complete through wm-1

    for (int t = 0; t < TSTEPS; t++) {
        // ---- xw for this step ----
        const unsigned short* xp = xw + ((size_t)t * BATCH + r2) * G4 + colbase + u0;
        u32x2 xi, xf, xg, xo;
        if (L == 0) {
            xi = *reinterpret_cast<const u32x2*>(xp);
            xf = *reinterpret_cast<const u32x2*>(xp + HDIM);
            xg = *reinterpret_cast<const u32x2*>(xp + 2 * HDIM);
            xo = *reinterpret_cast<const u32x2*>(xp + 3 * HDIM);
        } else {
            const int mt = t >> 1;
            while (mt >= wm) {
                int mti = wm + (lane >> 2); if (mti > 127) mti = 127;
                const unsigned* fp = gflags + mti * 32 + (lane & 3) * 8 + cb;
                unsigned v;
                asm volatile("global_load_dword %0, %1, off sc0 sc1" : "=v"(v) : "v"(fp));
                asm volatile("s_waitcnt vmcnt(0)" ::: "memory");
                __builtin_amdgcn_sched_barrier(0);
                unsigned long long mk = __ballot(v != 0);
                int adv = 0;
                while (adv < 16 && ((mk >> (4 * adv)) & 0xFull) == 0xFull) adv++;
                wm += adv;
                if (adv == 0) __builtin_amdgcn_s_sleep(16);
            }
            asm volatile("global_load_dwordx2 %0, %1, off sc0 sc1" : "=v"(xi) : "v"(xp));
            asm volatile("global_load_dwordx2 %0, %1, off sc0 sc1" : "=v"(xf) : "v"(xp + HDIM));
            asm volatile("global_load_dwordx2 %0, %1, off sc0 sc1" : "=v"(xg) : "v"(xp + 2 * HDIM));
            asm volatile("global_load_dwordx2 %0, %1, off sc0 sc1" : "=v"(xo) : "v"(xp + 3 * HDIM));
        }

        // ---- h(t-1) fragment base ----
        const unsigned short* pa0;
        if (t == 0) pa0 = h0b + (size_t)arow * HDIM + koff;
        else        pa0 = ring + ((size_t)(t - 1) * BATCH + arow) * HDIM + koff;
        const unsigned short* pa1 = pa0 + 16 * HDIM;
        const unsigned short* pa2 = pa0 + 32 * HDIM;
        const unsigned short* pa3 = pa0 + 48 * HDIM;

        // ---- load + sentinel-validate, direct retry (r10 proven) ----
        u32x4 afr[8][4];
#define ISSUE4(S, OFFS) \
        asm volatile("global_load_dwordx4 %0, %1, off offset:" OFFS " sc0 sc1" : "=v"(afr[S][0]) : "v"(pa0)); \
        asm volatile("global_load_dwordx4 %0, %1, off offset:" OFFS " sc0 sc1" : "=v"(afr[S][1]) : "v"(pa1)); \
        asm volatile("global_load_dwordx4 %0, %1, off offset:" OFFS " sc0 sc1" : "=v"(afr[S][2]) : "v"(pa2)); \
        asm volatile("global_load_dwordx4 %0, %1, off offset:" OFFS " sc0 sc1" : "=v"(afr[S][3]) : "v"(pa3));
        for (;;) {
            ISSUE4(0, "0")   ISSUE4(1, "64")  ISSUE4(2, "128") ISSUE4(3, "192")
            ISSUE4(4, "256") ISSUE4(5, "320") ISSUE4(6, "384") ISSUE4(7, "448")
            asm volatile("s_waitcnt vmcnt(0)" ::: "memory");
            __builtin_amdgcn_sched_barrier(0);
            unsigned mx = 0;
#pragma unroll
            for (int s = 0; s < 8; s++)
#pragma unroll
                for (int m = 0; m < 4; m++) {
                    u32x4 u = afr[s][m];
                    unsigned a = u[0] > u[1] ? u[0] : u[1];
                    unsigned b = u[2] > u[3] ? u[2] : u[3];
                    unsigned c = a > b ? a : b;
                    mx = mx > c ? mx : c;
                }
            if (!__any(mx >= 0xFFFF0000u)) break;
            __builtin_amdgcn_s_sleep(1);
        }
#undef ISSUE4

        // ---- MFMA ----
        f32x4 acc[4][4];
#pragma unroll
        for (int m = 0; m < 4; m++)
#pragma unroll
            for (int g = 0; g < 4; g++) acc[m][g] = (f32x4){0.f, 0.f, 0.f, 0.f};
#pragma unroll
        for (int s = 0; s < 8; s++)
#pragma unroll
            for (int m = 0; m < 4; m++) {
                short8 av = __builtin_bit_cast(short8, afr[s][m]);
#pragma unroll
                for (int g = 0; g < 4; g++)
                    acc[m][g] = __builtin_amdgcn_mfma_f32_16x16x32_bf16(
                        av, bfr[g][s], acc[m][g], 0, 0, 0);
            }

        // ---- pass A (gates i,f) ----
#pragma unroll
        for (int m = 0; m < 4; m++)
#pragma unroll
            for (int g = 0; g < 2; g++) {
                int col = g * 16 + (lane & 15);
                int rb = m * 16 + ((lane >> 4) << 2);
#pragma unroll
                for (int e = 0; e < 4; e++)
                    plds[kw][rb + e][col] = acc[m][g][e];
            }
        __syncthreads();
        f32x4 sI = (f32x4){0.f,0.f,0.f,0.f}, sF = sI;
#pragma unroll
        for (int w = 0; w < 4; w++) {
            sI += *reinterpret_cast<const f32x4*>(&plds[w][r2][u0]);
            sF += *reinterpret_cast<const f32x4*>(&plds[w][r2][16 + u0]);
        }
        __syncthreads();
        // ---- pass B (gates g,o) ----
#pragma unroll
        for (int m = 0; m < 4; m++)
#pragma unroll
            for (int g = 2; g < 4; g++) {
                int col = (g - 2) * 16 + (lane & 15);
                int rb = m * 16 + ((lane >> 4) << 2);
#pragma unroll
                for (int e = 0; e < 4; e++)
                    plds[kw][rb + e][col] = acc[m][g][e];
            }
        __syncthreads();
        f32x4 sG = (f32x4){0.f,0.f,0.f,0.f}, sO = sG;
#pragma unroll
        for (int w = 0; w < 4; w++) {
            sG += *reinterpret_cast<const f32x4*>(&plds[w][r2][u0]);
            sO += *reinterpret_cast<const f32x4*>(&plds[w][r2][16 + u0]);
        }
        __syncthreads();

#define ADDX(S, V) { unsigned lo = V[0], hi = V[1]; \
        S[0] += bf2f((unsigned short)lo); S[1] += bf2f((unsigned short)(lo >> 16)); \
        S[2] += bf2f((unsigned short)hi); S[3] += bf2f((unsigned short)(hi >> 16)); }
        ADDX(sI, xi) ADDX(sF, xf) ADDX(sG, xg) ADDX(sO, xo)
#undef ADDX

        float hv[4];
#pragma unroll
        for (int j = 0; j < 4; j++) {
            float c = sigf(sF[j]) * cst[j] + sigf(sI[j]) * tanhf_fast(sG[j]);
            cst[j] = c;
            hv[j] = sigf(sO[j]) * tanhf_fast(c);
        }
        u32x2 hp;
        hp[0] = (unsigned)f2bf(hv[0]) | ((unsigned)f2bf(hv[1]) << 16);
        hp[1] = (unsigned)f2bf(hv[2]) | ((unsigned)f2bf(hv[3]) << 16);
        unsigned short* wp = ring + ((size_t)t * BATCH + r2) * HDIM + colbase + u0;
        asm volatile("global_store_dwordx2 %0, %1, off sc0 sc1"
                     :: "v"(wp), "v"(hp) : "memory");

        if (t == TSTEPS - 1) {
            const size_t hi_ = (size_t)r2 * HDIM + colbase + u0;
            *reinterpret_cast<f32x4*>(hn + hi_) = (f32x4){hv[0], hv[1], hv[2], hv[3]};
            *reinterpret_cast<f32x4*>(cn + hi_) = cst;
        }
    }
}

// ---- persistent gemm body: xw1 = ring0 @ w1ib^T + bb1, t-ordered jobs, flags ----
static __device__ void gemm_body(const unsigned short* __restrict__ A,    // ring0
                                 const unsigned short* __restrict__ B,    // w1ib
                                 const float* __restrict__ bias,
                                 unsigned short* __restrict__ C,          // xw (in-place)
                                 unsigned* __restrict__ gflags,
                                 int gw, char* smem)
{
    unsigned short* As = reinterpret_cast<unsigned short*>(smem);
    unsigned short* Bs = As + BM * BK;
    const int tid = threadIdx.x;
    const int lane = tid & 63, wv = tid >> 6;
    const int wr = wv >> 1, wc = wv & 1;
    const int srow = tid >> 3;
    const int scb  = (tid & 7) * 16;
    const int JOBS = (128 * 32) / NGEMM;   // 128 per WG at NGEMM=32

    for (int i = 0; i < JOBS; i++) {
        const int j = i * NGEMM + gw;
        const int mt = j >> 5;
        const int nt = j & 31;
        const int bm0 = mt * BM, bn0 = nt * BN;

        {
            const unsigned short* lr = A + ((size_t)bm0 + 127) * HDIM + lane * 16;
            for (;;) {
                unsigned v;
                asm volatile("global_load_dword %0, %1, off sc0 sc1" : "=v"(v) : "v"(lr));
                asm volatile("s_waitcnt vmcnt(0)" ::: "memory");
                __builtin_amdgcn_sched_barrier(0);
                if (!__any(v >= 0xFFFF0000u)) break;
                __builtin_amdgcn_s_sleep(64);
            }
        }

        f32x4 acc[4][4];
#pragma unroll
        for (int a = 0; a < 4; a++)
#pragma unroll
            for (int b = 0; b < 4; b++) acc[a][b] = (f32x4){0.f, 0.f, 0.f, 0.f};

        for (int kt = 0; kt < HDIM; kt += BK) {
            __syncthreads();
#pragma unroll
            for (int is = 0; is < 4; is++) {
                int row = is * 32 + srow;
                int kb = scb ^ ((row & 7) << 4);
                g2l16(B + (size_t)(bn0 + row) * HDIM + kt + (kb >> 1),
                      (char*)Bs + is * 4096 + wv * 1024);
            }
            const unsigned short* ap[4];
#pragma unroll
            for (int is = 0; is < 4; is++) {
                int row = is * 32 + srow;
                int kb = scb ^ ((row & 7) << 4);
                ap[is] = A + (size_t)(bm0 + row) * HDIM + kt + (kb >> 1);
            }
            u32x4 av0, av1, av2, av3;
            for (;;) {
                asm volatile("global_load_dwordx4 %0, %1, off sc0 sc1" : "=v"(av0) : "v"(ap[0]));
                asm volatile("global_load_dwordx4 %0, %1, off sc0 sc1" : "=v"(av1) : "v"(ap[1]));
                asm volatile("global_load_dwordx4 %0, %1, off sc0 sc1" : "=v"(av2) : "v"(ap[2]));
                asm volatile("global_load_dwordx4 %0, %1, off sc0 sc1" : "=v"(av3) : "v"(ap[3]));
                asm volatile("s_waitcnt vmcnt(0)" ::: "memory");
                __builtin_amdgcn_sched_barrier(0);
                unsigned mx = 0;
#pragma unroll
                for (int e = 0; e < 4; e++) {
                    unsigned a01 = av0[e] > av1[e] ? av0[e] : av1[e];
                    unsigned a23 = av2[e] > av3[e] ? av2[e] : av3[e];
                    unsigned m = a01 > a23 ? a01 : a23;
                    mx = mx > m ? mx : m;
                }
                if (mx < 0xFFFF0000u) break;
                __builtin_amdgcn_s_sleep(2);
            }
            char* asb = (char*)As;
            *reinterpret_cast<u32x4*>(asb + 0 * 4096 + wv * 1024 + lane * 16) = av0;
            *reinterpret_cast<u32x4*>(asb + 1 * 4096 + wv * 1024 + lane * 16) = av1;
            *reinterpret_cast<u32x4*>(asb + 2 * 4096 + wv * 1024 + lane * 16) = av2;
            *reinterpret_cast<u32x4*>(asb + 3 * 4096 + wv * 1024 + lane * 16) = av3;
            __syncthreads();

#pragma unroll
            for (int ks = 0; ks < 2; ks++) {
                short8 a[4], b[4];
                const int kb = ks * 64 + ((lane >> 4) << 4);
#pragma unroll
                for (int m = 0; m < 4; m++) {
                    int r = wr * 64 + m * 16 + (lane & 15);
                    a[m] = *reinterpret_cast<const short8*>(
                        (const char*)As + r * 128 + (kb ^ ((r & 7) << 4)));
                }
#pragma unroll
                for (int n = 0; n < 4; n++) {
                    int nn = wc * 64 + n * 16 + (lane & 15);
                    b[n] = *reinterpret_cast<const short8*>(
                        (const char*)Bs + nn * 128 + (kb ^ ((nn & 7) << 4)));
                }
#pragma unroll
                for (int m = 0; m < 4; m++)
#pragma unroll
                    for (int n = 0; n < 4; n++)
                        acc[m][n] = __builtin_amdgcn_mfma_f32_16x16x32_bf16(
                            a[m], b[n], acc[m][n], 0, 0, 0);
            }
        }

#pragma unroll
        for (int n = 0; n < 4; n++) {
            int cg = bn0 + wc * 64 + n * 16 + (lane & 15);
            float bv = bias[cg];
#pragma unroll
            for (int m = 0; m < 4; m++) {
#pragma unroll
                for (int e = 0; e < 4; e++) {
                    int rg = bm0 + wr * 64 + m * 16 + ((lane >> 4) << 2) + e;
                    unsigned val = f2bf(acc[m][n][e] + bv);
                    const unsigned short* cp = C + (size_t)rg * G4 + cg;
                    asm volatile("global_store_short %0, %1, off sc0 sc1"
                                 :: "v"(cp), "v"(val) : "memory");
                }
            }
        }
        asm volatile("s_waitcnt vmcnt(0)" ::: "memory");
        __syncthreads();
        if (tid == 0) {
            unsigned one = 1;
            asm volatile("global_store_dword %0, %1, off sc0 sc1"
                         :: "v"(gflags + mt * 32 + nt), "v"(one) : "memory");
        }
    }
}

__global__ __launch_bounds__(256, 1)
void k_fused(const unsigned short* __restrict__ w0hb,
             const unsigned short* __restrict__ w1hb,
             const unsigned short* __restrict__ w1ib,
             const float* __restrict__ bb1,
             unsigned short* __restrict__ xw,
             unsigned short* __restrict__ ring0,
             unsigned short* __restrict__ ring1,
             const float* __restrict__ c0,
             const unsigned short* __restrict__ hA0,
             const unsigned short* __restrict__ hA1,
             float* __restrict__ hn, float* __restrict__ cn,
             unsigned* __restrict__ gflags)
{
    __shared__ alignas(16) char smem[4 * 64 * 34 * 4];
    const int bid = blockIdx.x;
    if (bid < NSCAN) {
        scan_body<0>(w0hb, xw, c0, hA0, ring0, hn, cn, nullptr, bid, smem);
    } else if (bid < NSCAN + NGEMM) {
        gemm_body(ring0, w1ib, bb1, xw, gflags, bid - NSCAN, smem);
    } else {
        scan_body<1>(w1hb, xw, c0 + BATCH * HDIM, hA1, ring1,
                     hn + BATCH * HDIM, cn + BATCH * HDIM,
                     gflags, bid - NSCAN - NGEMM, smem);
    }
}

// ---------------- decode + log_softmax ----------------
__global__ __launch_bounds__(256)
void k_decode(const float* __restrict__ h1,
              const float* __restrict__ wdec,
              const float* __restrict__ bdec,
              float* __restrict__ out)
{
    __shared__ float hs[HDIM];
    __shared__ float ls[NINPUT];
    __shared__ float red[256];
    const int r = blockIdx.x, tid = threadIdx.x;
    reinterpret_cast<float4*>(hs)[tid] = reinterpret_cast<const float4*>(h1 + (size_t)r * HDIM)[tid];
    __syncthreads();
#pragma unroll
    for (int rep = 0; rep < 2; rep++) {
        int n = tid + rep * 256;
        float s = bdec[n];
        const float4* w4 = reinterpret_cast<const float4*>(wdec + (size_t)n * HDIM);
        for (int k = 0; k < HDIM / 4; k++) {
            float4 w = w4[k];
            float4 h4 = reinterpret_cast<const float4*>(hs)[k];
            s += w.x * h4.x + w.y * h4.y + w.z * h4.z + w.w * h4.w;
        }
        ls[n] = s;
    }
    __syncthreads();
    red[tid] = fmaxf(ls[tid], ls[tid + 256]);
    __syncthreads();
    for (int s2 = 128; s2 > 0; s2 >>= 1) {
        if (tid < s2) red[tid] = fmaxf(red[tid], red[tid + s2]);
        __syncthreads();
    }
    float M = red[0];
    __syncthreads();
    red[tid] = __expf(ls[tid] - M) + __expf(ls[tid + 256] - M);
    __syncthreads();
    for (int s2 = 128; s2 > 0; s2 >>= 1) {
        if (tid < s2) red[tid] += red[tid + s2];
        __syncthreads();
    }
    float lse = M + __logf(red[0]);
    out[(size_t)r * NINPUT + tid] = ls[tid] - lse;
    out[(size_t)r * NINPUT + tid + 256] = ls[tid + 256] - lse;
}

// ---------------- host launcher ----------------
extern "C" void kernel_launch(void* const* d_in, const int* in_sizes, int n_in,
                              void* d_out, int out_size, void* d_ws, size_t ws_size,
                              hipStream_t stream)
{
    const float* x    = (const float*)d_in[0];
    const float* h0   = (const float*)d_in[1];
    const float* c0   = (const float*)d_in[2];
    const float* wih0 = (const float*)d_in[3];
    const float* whh0 = (const float*)d_in[4];
    const float* bih0 = (const float*)d_in[5];
    const float* bhh0 = (const float*)d_in[6];
    const float* wih1 = (const float*)d_in[7];
    const float* whh1 = (const float*)d_in[8];
    const float* bih1 = (const float*)d_in[9];
    const float* bhh1 = (const float*)d_in[10];
    const float* wdec = (const float*)d_in[11];
    const float* bdec = (const float*)d_in[12];
    float* out = (float*)d_out;

    char* ws = (char*)d_ws;
    size_t off = 0;
    auto alloc = [&](size_t bytes) -> void* {
        void* p = ws + off;
        off += (bytes + 255) & ~(size_t)255;
        return p;
    };
    const size_t ring_bytes = (size_t)TSTEPS * BATCH * HDIM * 2;   // 33.5 MB

    unsigned short* xw    = (unsigned short*)alloc((size_t)BATCH * TSTEPS * G4 * 2);   // 134.2 MB time-major
    unsigned short* ring0 = (unsigned short*)alloc(ring_bytes);                        // 33.5 MB time-major
    unsigned short* w0hb  = (unsigned short*)alloc((size_t)G4 * HDIM * 2);
    unsigned short* w1ib  = (unsigned short*)alloc((size_t)G4 * HDIM * 2);
    unsigned short* w1hb  = (unsigned short*)alloc((size_t)G4 * HDIM * 2);
    float*          bb0   = (float*)alloc(G4 * 4);
    float*          bb1   = (float*)alloc(G4 * 4);
    unsigned short* hA0   = (unsigned short*)alloc(BATCH * HDIM * 2);
    unsigned short* hA1   = (unsigned short*)alloc(BATCH * HDIM * 2);
    unsigned*       gflags = (unsigned*)alloc(128 * 32 * 4);
    // ring1 overlays xb + w0ib (dead after gemm0) + explicit pad
    unsigned short* xb    = (unsigned short*)alloc((size_t)TSTEPS * BATCH * NINPUT * 2); // 16.8 MB
    unsigned short* w0ib  = (unsigned short*)alloc((size_t)G4 * NINPUT * 2);             // 4.2 MB
    unsigned short* ring1 = xb;
    {
        size_t have = (size_t)TSTEPS * BATCH * NINPUT * 2 + (size_t)G4 * NINPUT * 2;
        if (ring_bytes > have) alloc(ring_bytes - have);                                 // 12.6 MB pad
    }

    const long ring_n4 = (long)ring_bytes / 16;

    // single prologue kernel: conversions + biases + h0 + ring0 poison + gflags clear
    k_prep_all<<<2048, 256, 0, stream>>>(x, xb, wih0, w0ib, whh0, w0hb,
                                         wih1, w1ib, whh1, w1hb,
                                         bih0, bhh0, bb0, bih1, bhh1, bb1,
                                         h0, hA0, hA1, (u32x4*)ring0, gflags);

    const int M = BATCH * TSTEPS;
    // layer 0 input projection (time-major rows): xw0 = xb @ wih0^T + (bih0+bhh0)
    k_gemm_bt<<<(M / BM) * (G4 / BN), 256, 0, stream>>>(xb, w0ib, bb0, xw, M, G4, NINPUT);

    // xb/w0ib now dead -> poison ring1 (full-T sentinel ring for scan1)
    k_poison<<<2048, 256, 0, stream>>>((u32x4*)ring1, ring_n4);

    // fused pipeline: scan0 | gemm1 (xw overwritten in place) | scan1
    k_fused<<<NSCAN + NGEMM + NSCAN, 256, 0, stream>>>(
        w0hb, w1hb, w1ib, bb1, xw, ring0, ring1, c0, hA0, hA1,
        out + 32768,
        out + 32768 + 2 * BATCH * HDIM,
        gflags);

    // decode from fp32 final h of layer 1
    k_decode<<<BATCH, 256, 0, stream>>>(out + 32768 + BATCH * HDIM, wdec, bdec, out);
}

// Round 14
// 2718.205 us; speedup vs baseline: 1.0709x; 1.0020x over previous
//
#include <hip/hip_runtime.h>

#define BATCH   64
#define TSTEPS  256
#define NINPUT  512
#define HDIM    1024
#define G4      4096   // 4*HDIM
#define NSCAN   64     // scan WGs per layer
#define NHC     16     // h-columns per scan WG
#define NGEMM   32     // persistent gemm WGs

typedef __attribute__((ext_vector_type(8))) short short8;
typedef __attribute__((ext_vector_type(4))) float f32x4;
typedef __attribute__((ext_vector_type(4))) unsigned int u32x4;
typedef __attribute__((ext_vector_type(2))) unsigned int u32x2;

static __device__ __forceinline__ unsigned short f2bf(float x) {
    unsigned u = __float_as_uint(x);
    unsigned r = 0x7fffu + ((u >> 16) & 1u);
    return (unsigned short)((u + r) >> 16);
}
static __device__ __forceinline__ float bf2f(unsigned short b) {
    return __uint_as_float(((unsigned)b) << 16);
}
static __device__ __forceinline__ float sigf(float x) {
    return 1.f / (1.f + __expf(-x));
}
static __device__ __forceinline__ float tanhf_fast(float x) {
    return 2.f / (1.f + __expf(-2.f * x)) - 1.f;
}

// ---------------- poison ring with bf16-NaN sentinel ----------------
__global__ void k_poison(u32x4* __restrict__ p, long n4) {
    long i = (long)blockIdx.x * blockDim.x + threadIdx.x;
    long st = (long)gridDim.x * blockDim.x;
    u32x4 v = (u32x4){0xFFFFFFFFu, 0xFFFFFFFFu, 0xFFFFFFFFu, 0xFFFFFFFFu};
    for (; i < n4; i += st) p[i] = v;
}

// ---------------- ALL prologue prep in one launch ----------------
__global__ void k_prep_all(const float* __restrict__ x,    unsigned short* __restrict__ xb,
                           const float* __restrict__ wih0, unsigned short* __restrict__ w0ib,
                           const float* __restrict__ whh0, unsigned short* __restrict__ w0hb,
                           const float* __restrict__ wih1, unsigned short* __restrict__ w1ib,
                           const float* __restrict__ whh1, unsigned short* __restrict__ w1hb,
                           const float* __restrict__ bih0, const float* __restrict__ bhh0,
                           float* __restrict__ bb0,
                           const float* __restrict__ bih1, const float* __restrict__ bhh1,
                           float* __restrict__ bb1,
                           const float* __restrict__ h0,
                           unsigned short* __restrict__ hA0, unsigned short* __restrict__ hA1,
                           u32x4* __restrict__ ring0p, unsigned* __restrict__ gflags)
{
    const long tid0 = (long)blockIdx.x * blockDim.x + threadIdx.x;
    const long nthr = (long)gridDim.x * blockDim.x;

    // x -> xb with [B][T] -> [T][B] transpose (float4 granularity)
    {
        const long total4 = (long)BATCH * TSTEPS * NINPUT / 4;
        for (long i = tid0; i < total4; i += nthr) {
            long v = i * 4;
            long row = v / NINPUT;
            int ii = (int)(v - row * NINPUT);
            int b = (int)(row / TSTEPS);
            int t = (int)(row - (long)b * TSTEPS);
            float4 f = *reinterpret_cast<const float4*>(x + v);
            ushort4 o;
            o.x = f2bf(f.x); o.y = f2bf(f.y); o.z = f2bf(f.z); o.w = f2bf(f.w);
            *reinterpret_cast<ushort4*>(xb + ((size_t)t * BATCH + b) * NINPUT + ii) = o;
        }
    }
#define CVT(SRC, DST, N) { \
        const long n4 = (long)(N) / 4; \
        for (long i = tid0; i < n4; i += nthr) { \
            float4 f = *reinterpret_cast<const float4*>((SRC) + i * 4); \
            ushort4 o; \
            o.x = f2bf(f.x); o.y = f2bf(f.y); o.z = f2bf(f.z); o.w = f2bf(f.w); \
            *reinterpret_cast<ushort4*>((DST) + i * 4) = o; \
        } }
    CVT(wih0, w0ib, (long)G4 * NINPUT)
    CVT(whh0, w0hb, (long)G4 * HDIM)
    CVT(wih1, w1ib, (long)G4 * HDIM)
    CVT(whh1, w1hb, (long)G4 * HDIM)
#undef CVT
    for (long i = tid0; i < G4; i += nthr) {
        bb0[i] = bih0[i] + bhh0[i];
        bb1[i] = bih1[i] + bhh1[i];
    }
    for (long i = tid0; i < BATCH * HDIM; i += nthr) {
        hA0[i] = f2bf(h0[i]);
        hA1[i] = f2bf(h0[BATCH * HDIM + i]);
    }
    {
        const long n4 = (long)TSTEPS * BATCH * HDIM * 2 / 16;
        u32x4 v = (u32x4){0xFFFFFFFFu, 0xFFFFFFFFu, 0xFFFFFFFFu, 0xFFFFFFFFu};
        for (long i = tid0; i < n4; i += nthr) ring0p[i] = v;
    }
    for (long i = tid0; i < 128 * 32; i += nthr) gflags[i] = 0;
}

// ---------------- standalone bf16 GEMM (layer-0 input projection) ----------------
#define BM 128
#define BN 128
#define BK 64

static __device__ __forceinline__ void g2l16(const unsigned short* g, void* lds) {
    __builtin_amdgcn_global_load_lds(
        (const __attribute__((address_space(1))) unsigned int*)g,
        (__attribute__((address_space(3))) unsigned int*)lds, 16, 0, 0);
}

__global__ __launch_bounds__(256)
void k_gemm_bt(const unsigned short* __restrict__ A,
               const unsigned short* __restrict__ B,
               const float* __restrict__ bias,
               unsigned short* __restrict__ C,
               int M, int N, int K)
{
    __shared__ unsigned short As[BM * BK];
    __shared__ unsigned short Bs[BN * BK];
    const int tid = threadIdx.x;
    const int lane = tid & 63, wv = tid >> 6;
    const int nbn = N / BN;
    const int bm0 = (blockIdx.x / nbn) * BM;
    const int bn0 = (blockIdx.x % nbn) * BN;
    const int wr = wv >> 1, wc = wv & 1;

    f32x4 acc[4][4];
#pragma unroll
    for (int i = 0; i < 4; i++)
#pragma unroll
        for (int j = 0; j < 4; j++) acc[i][j] = (f32x4){0.f, 0.f, 0.f, 0.f};

    const int srow = tid >> 3;
    const int scb  = (tid & 7) * 16;

    for (int kt = 0; kt < K; kt += BK) {
        __syncthreads();
#pragma unroll
        for (int is = 0; is < 4; is++) {
            int row = is * 32 + srow;
            int kb = scb ^ ((row & 7) << 4);
            g2l16(A + (size_t)(bm0 + row) * K + kt + (kb >> 1),
                  (char*)As + is * 4096 + wv * 1024);
        }
#pragma unroll
        for (int is = 0; is < 4; is++) {
            int row = is * 32 + srow;
            int kb = scb ^ ((row & 7) << 4);
            g2l16(B + (size_t)(bn0 + row) * K + kt + (kb >> 1),
                  (char*)Bs + is * 4096 + wv * 1024);
        }
        asm volatile("s_waitcnt vmcnt(0)" ::: "memory");
        __syncthreads();

#pragma unroll
        for (int ks = 0; ks < 2; ks++) {
            short8 a[4], b[4];
            const int kb = ks * 64 + ((lane >> 4) << 4);
#pragma unroll
            for (int mt = 0; mt < 4; mt++) {
                int r = wr * 64 + mt * 16 + (lane & 15);
                a[mt] = *reinterpret_cast<const short8*>(
                    (const char*)As + r * 128 + (kb ^ ((r & 7) << 4)));
            }
#pragma unroll
            for (int nt = 0; nt < 4; nt++) {
                int n = wc * 64 + nt * 16 + (lane & 15);
                b[nt] = *reinterpret_cast<const short8*>(
                    (const char*)Bs + n * 128 + (kb ^ ((n & 7) << 4)));
            }
#pragma unroll
            for (int mt = 0; mt < 4; mt++)
#pragma unroll
                for (int nt = 0; nt < 4; nt++)
                    acc[mt][nt] = __builtin_amdgcn_mfma_f32_16x16x32_bf16(
                        a[mt], b[nt], acc[mt][nt], 0, 0, 0);
        }
    }

#pragma unroll
    for (int nt = 0; nt < 4; nt++) {
        int cg = bn0 + wc * 64 + nt * 16 + (lane & 15);
        float bv = bias[cg];
#pragma unroll
        for (int mt = 0; mt < 4; mt++) {
#pragma unroll
            for (int e = 0; e < 4; e++) {
                int rg = bm0 + wr * 64 + mt * 16 + ((lane >> 4) << 2) + e;
                C[(size_t)rg * N + cg] = f2bf(acc[mt][nt][e] + bv);
            }
        }
    }
}

// =====================================================================
// Fused pipeline: scan0 (WG 0-63) | gemm1 (WG 64-95) | scan1 (WG 96-159)
// Time-major: xw rows = t*64+b; ring slot t = [64][1024] bf16 contiguous.
// Scans: full-T sentinel rings + SINGLE-PASS LDS reduce (plds[4][64][68],
// all 4 gates written at once; 2 barriers/step instead of 4).
// =====================================================================

#define PLDS_W 68   // 64 cols (4 gates x 16) + 4 pad -> stride = 4 mod 32 banks

template<int L>
static __device__ void scan_body(const unsigned short* __restrict__ whh,
                                 const unsigned short* __restrict__ xw,
                                 const float* __restrict__ c0,
                                 const unsigned short* __restrict__ h0b,
                                 unsigned short* __restrict__ ring,   // [T][64][1024] bf16, poisoned
                                 float* __restrict__ hn, float* __restrict__ cn,
                                 const unsigned* __restrict__ gflags,
                                 int wg, char* smem)
{
    float (*plds)[64][PLDS_W] = reinterpret_cast<float (*)[64][PLDS_W]>(smem);
    const int tid = threadIdx.x;
    const int lane = tid & 63, kw = tid >> 6;
    const int colbase = wg * NHC;
    const int cb = wg >> 3;     // n-tile sub-index for gemm flags

    short8 bfr[4][8];
    {
        const int c = lane & 15;
#pragma unroll
        for (int g = 0; g < 4; g++) {
            int grow = g * HDIM + colbase + c;
#pragma unroll
            for (int s = 0; s < 8; s++) {
                int k = kw * 256 + s * 32 + ((lane >> 4) << 3);
                bfr[g][s] = *reinterpret_cast<const short8*>(whh + (size_t)grow * HDIM + k);
            }
        }
    }

    const int r2 = tid >> 2;
    const int u0 = (tid & 3) * 4;
    f32x4 cst = *reinterpret_cast<const f32x4*>(c0 + (size_t)r2 * HDIM + colbase + u0);

    const int arow = lane & 15;
    const size_t koff = (size_t)kw * 256 + ((lane >> 4) << 3);
    int wm = 0;   // L==1: gemm m-tiles complete through wm-1

    for (int t = 0; t < TSTEPS; t++) {
        // ---- xw for this step ----
        const unsigned short* xp = xw + ((size_t)t * BATCH + r2) * G4 + colbase + u0;
        u32x2 xi, xf, xg, xo;
        if (L == 0) {
            xi = *reinterpret_cast<const u32x2*>(xp);
            xf = *reinterpret_cast<const u32x2*>(xp + HDIM);
            xg = *reinterpret_cast<const u32x2*>(xp + 2 * HDIM);
            xo = *reinterpret_cast<const u32x2*>(xp + 3 * HDIM);
        } else {
            const int mt = t >> 1;
            while (mt >= wm) {
                int mti = wm + (lane >> 2); if (mti > 127) mti = 127;
                const unsigned* fp = gflags + mti * 32 + (lane & 3) * 8 + cb;
                unsigned v;
                asm volatile("global_load_dword %0, %1, off sc0 sc1" : "=v"(v) : "v"(fp));
                asm volatile("s_waitcnt vmcnt(0)" ::: "memory");
                __builtin_amdgcn_sched_barrier(0);
                unsigned long long mk = __ballot(v != 0);
                int adv = 0;
                while (adv < 16 && ((mk >> (4 * adv)) & 0xFull) == 0xFull) adv++;
                wm += adv;
                if (adv == 0) __builtin_amdgcn_s_sleep(16);
            }
            asm volatile("global_load_dwordx2 %0, %1, off sc0 sc1" : "=v"(xi) : "v"(xp));
            asm volatile("global_load_dwordx2 %0, %1, off sc0 sc1" : "=v"(xf) : "v"(xp + HDIM));
            asm volatile("global_load_dwordx2 %0, %1, off sc0 sc1" : "=v"(xg) : "v"(xp + 2 * HDIM));
            asm volatile("global_load_dwordx2 %0, %1, off sc0 sc1" : "=v"(xo) : "v"(xp + 3 * HDIM));
        }

        // ---- h(t-1) fragment base ----
        const unsigned short* pa0;
        if (t == 0) pa0 = h0b + (size_t)arow * HDIM + koff;
        else        pa0 = ring + ((size_t)(t - 1) * BATCH + arow) * HDIM + koff;
        const unsigned short* pa1 = pa0 + 16 * HDIM;
        const unsigned short* pa2 = pa0 + 32 * HDIM;
        const unsigned short* pa3 = pa0 + 48 * HDIM;

        // ---- load + sentinel-validate, direct retry (r10 proven) ----
        u32x4 afr[8][4];
#define ISSUE4(S, OFFS) \
        asm volatile("global_load_dwordx4 %0, %1, off offset:" OFFS " sc0 sc1" : "=v"(afr[S][0]) : "v"(pa0)); \
        asm volatile("global_load_dwordx4 %0, %1, off offset:" OFFS " sc0 sc1" : "=v"(afr[S][1]) : "v"(pa1)); \
        asm volatile("global_load_dwordx4 %0, %1, off offset:" OFFS " sc0 sc1" : "=v"(afr[S][2]) : "v"(pa2)); \
        asm volatile("global_load_dwordx4 %0, %1, off offset:" OFFS " sc0 sc1" : "=v"(afr[S][3]) : "v"(pa3));
        for (;;) {
            ISSUE4(0, "0")   ISSUE4(1, "64")  ISSUE4(2, "128") ISSUE4(3, "192")
            ISSUE4(4, "256") ISSUE4(5, "320") ISSUE4(6, "384") ISSUE4(7, "448")
            asm volatile("s_waitcnt vmcnt(0)" ::: "memory");
            __builtin_amdgcn_sched_barrier(0);
            unsigned mx = 0;
#pragma unroll
            for (int s = 0; s < 8; s++)
#pragma unroll
                for (int m = 0; m < 4; m++) {
                    u32x4 u = afr[s][m];
                    unsigned a = u[0] > u[1] ? u[0] : u[1];
                    unsigned b = u[2] > u[3] ? u[2] : u[3];
                    unsigned c = a > b ? a : b;
                    mx = mx > c ? mx : c;
                }
            if (!__any(mx >= 0xFFFF0000u)) break;
            __builtin_amdgcn_s_sleep(1);
        }
#undef ISSUE4

        // ---- MFMA ----
        f32x4 acc[4][4];
#pragma unroll
        for (int m = 0; m < 4; m++)
#pragma unroll
            for (int g = 0; g < 4; g++) acc[m][g] = (f32x4){0.f, 0.f, 0.f, 0.f};
#pragma unroll
        for (int s = 0; s < 8; s++)
#pragma unroll
            for (int m = 0; m < 4; m++) {
                short8 av = __builtin_bit_cast(short8, afr[s][m]);
#pragma unroll
                for (int g = 0; g < 4; g++)
                    acc[m][g] = __builtin_amdgcn_mfma_f32_16x16x32_bf16(
                        av, bfr[g][s], acc[m][g], 0, 0, 0);
            }

        // ---- single-pass LDS reduce: all 4 gates at once ----
#pragma unroll
        for (int m = 0; m < 4; m++)
#pragma unroll
            for (int g = 0; g < 4; g++) {
                int col = g * 16 + (lane & 15);
                int rb = m * 16 + ((lane >> 4) << 2);
#pragma unroll
                for (int e = 0; e < 4; e++)
                    plds[kw][rb + e][col] = acc[m][g][e];
            }
        __syncthreads();
        f32x4 sI = (f32x4){0.f,0.f,0.f,0.f}, sF = sI, sG = sI, sO = sI;
#pragma unroll
        for (int w = 0; w < 4; w++) {
            sI += *reinterpret_cast<const f32x4*>(&plds[w][r2][u0]);
            sF += *reinterpret_cast<const f32x4*>(&plds[w][r2][16 + u0]);
            sG += *reinterpret_cast<const f32x4*>(&plds[w][r2][32 + u0]);
            sO += *reinterpret_cast<const f32x4*>(&plds[w][r2][48 + u0]);
        }
        __syncthreads();   // plds reusable next step

#define ADDX(S, V) { unsigned lo = V[0], hi = V[1]; \
        S[0] += bf2f((unsigned short)lo); S[1] += bf2f((unsigned short)(lo >> 16)); \
        S[2] += bf2f((unsigned short)hi); S[3] += bf2f((unsigned short)(hi >> 16)); }
        ADDX(sI, xi) ADDX(sF, xf) ADDX(sG, xg) ADDX(sO, xo)
#undef ADDX

        float hv[4];
#pragma unroll
        for (int j = 0; j < 4; j++) {
            float c = sigf(sF[j]) * cst[j] + sigf(sI[j]) * tanhf_fast(sG[j]);
            cst[j] = c;
            hv[j] = sigf(sO[j]) * tanhf_fast(c);
        }
        u32x2 hp;
        hp[0] = (unsigned)f2bf(hv[0]) | ((unsigned)f2bf(hv[1]) << 16);
        hp[1] = (unsigned)f2bf(hv[2]) | ((unsigned)f2bf(hv[3]) << 16);
        unsigned short* wp = ring + ((size_t)t * BATCH + r2) * HDIM + colbase + u0;
        asm volatile("global_store_dwordx2 %0, %1, off sc0 sc1"
                     :: "v"(wp), "v"(hp) : "memory");

        if (t == TSTEPS - 1) {
            const size_t hi_ = (size_t)r2 * HDIM + colbase + u0;
            *reinterpret_cast<f32x4*>(hn + hi_) = (f32x4){hv[0], hv[1], hv[2], hv[3]};
            *reinterpret_cast<f32x4*>(cn + hi_) = cst;
        }
    }
}

// ---- persistent gemm body: xw1 = ring0 @ w1ib^T + bb1, t-ordered jobs, flags ----
static __device__ void gemm_body(const unsigned short* __restrict__ A,    // ring0
                                 const unsigned short* __restrict__ B,    // w1ib
                                 const float* __restrict__ bias,
                                 unsigned short* __restrict__ C,          // xw (in-place)
                                 unsigned* __restrict__ gflags,
                                 int gw, char* smem)
{
    unsigned short* As = reinterpret_cast<unsigned short*>(smem);
    unsigned short* Bs = As + BM * BK;
    const int tid = threadIdx.x;
    const int lane = tid & 63, wv = tid >> 6;
    const int wr = wv >> 1, wc = wv & 1;
    const int srow = tid >> 3;
    const int scb  = (tid & 7) * 16;
    const int JOBS = (128 * 32) / NGEMM;

    for (int i = 0; i < JOBS; i++) {
        const int j = i * NGEMM + gw;
        const int mt = j >> 5;
        const int nt = j & 31;
        const int bm0 = mt * BM, bn0 = nt * BN;

        {
            const unsigned short* lr = A + ((size_t)bm0 + 127) * HDIM + lane * 16;
            for (;;) {
                unsigned v;
                asm volatile("global_load_dword %0, %1, off sc0 sc1" : "=v"(v) : "v"(lr));
                asm volatile("s_waitcnt vmcnt(0)" ::: "memory");
                __builtin_amdgcn_sched_barrier(0);
                if (!__any(v >= 0xFFFF0000u)) break;
                __builtin_amdgcn_s_sleep(64);
            }
        }

        f32x4 acc[4][4];
#pragma unroll
        for (int a = 0; a < 4; a++)
#pragma unroll
            for (int b = 0; b < 4; b++) acc[a][b] = (f32x4){0.f, 0.f, 0.f, 0.f};

        for (int kt = 0; kt < HDIM; kt += BK) {
            __syncthreads();
#pragma unroll
            for (int is = 0; is < 4; is++) {
                int row = is * 32 + srow;
                int kb = scb ^ ((row & 7) << 4);
                g2l16(B + (size_t)(bn0 + row) * HDIM + kt + (kb >> 1),
                      (char*)Bs + is * 4096 + wv * 1024);
            }
            const unsigned short* ap[4];
#pragma unroll
            for (int is = 0; is < 4; is++) {
                int row = is * 32 + srow;
                int kb = scb ^ ((row & 7) << 4);
                ap[is] = A + (size_t)(bm0 + row) * HDIM + kt + (kb >> 1);
            }
            u32x4 av0, av1, av2, av3;
            for (;;) {
                asm volatile("global_load_dwordx4 %0, %1, off sc0 sc1" : "=v"(av0) : "v"(ap[0]));
                asm volatile("global_load_dwordx4 %0, %1, off sc0 sc1" : "=v"(av1) : "v"(ap[1]));
                asm volatile("global_load_dwordx4 %0, %1, off sc0 sc1" : "=v"(av2) : "v"(ap[2]));
                asm volatile("global_load_dwordx4 %0, %1, off sc0 sc1" : "=v"(av3) : "v"(ap[3]));
                asm volatile("s_waitcnt vmcnt(0)" ::: "memory");
                __builtin_amdgcn_sched_barrier(0);
                unsigned mx = 0;
#pragma unroll
                for (int e = 0; e < 4; e++) {
                    unsigned a01 = av0[e] > av1[e] ? av0[e] : av1[e];
                    unsigned a23 = av2[e] > av3[e] ? av2[e] : av3[e];
                    unsigned m = a01 > a23 ? a01 : a23;
                    mx = mx > m ? mx : m;
                }
                if (mx < 0xFFFF0000u) break;
                __builtin_amdgcn_s_sleep(2);
            }
            char* asb = (char*)As;
            *reinterpret_cast<u32x4*>(asb + 0 * 4096 + wv * 1024 + lane * 16) = av0;
            *reinterpret_cast<u32x4*>(asb + 1 * 4096 + wv * 1024 + lane * 16) = av1;
            *reinterpret_cast<u32x4*>(asb + 2 * 4096 + wv * 1024 + lane * 16) = av2;
            *reinterpret_cast<u32x4*>(asb + 3 * 4096 + wv * 1024 + lane * 16) = av3;
            __syncthreads();

#pragma unroll
            for (int ks = 0; ks < 2; ks++) {
                short8 a[4], b[4];
                const int kb = ks * 64 + ((lane >> 4) << 4);
#pragma unroll
                for (int m = 0; m < 4; m++) {
                    int r = wr * 64 + m * 16 + (lane & 15);
                    a[m] = *reinterpret_cast<const short8*>(
                        (const char*)As + r * 128 + (kb ^ ((r & 7) << 4)));
                }
#pragma unroll
                for (int n = 0; n < 4; n++) {
                    int nn = wc * 64 + n * 16 + (lane & 15);
                    b[n] = *reinterpret_cast<const short8*>(
                        (const char*)Bs + nn * 128 + (kb ^ ((nn & 7) << 4)));
                }
#pragma unroll
                for (int m = 0; m < 4; m++)
#pragma unroll
                    for (int n = 0; n < 4; n++)
                        acc[m][n] = __builtin_amdgcn_mfma_f32_16x16x32_bf16(
                            a[m], b[n], acc[m][n], 0, 0, 0);
            }
        }

#pragma unroll
        for (int n = 0; n < 4; n++) {
            int cg = bn0 + wc * 64 + n * 16 + (lane & 15);
            float bv = bias[cg];
#pragma unroll
            for (int m = 0; m < 4; m++) {
#pragma unroll
                for (int e = 0; e < 4; e++) {
                    int rg = bm0 + wr * 64 + m * 16 + ((lane >> 4) << 2) + e;
                    unsigned val = f2bf(acc[m][n][e] + bv);
                    const unsigned short* cp = C + (size_t)rg * G4 + cg;
                    asm volatile("global_store_short %0, %1, off sc0 sc1"
                                 :: "v"(cp), "v"(val) : "memory");
                }
            }
        }
        asm volatile("s_waitcnt vmcnt(0)" ::: "memory");
        __syncthreads();
        if (tid == 0) {
            unsigned one = 1;
            asm volatile("global_store_dword %0, %1, off sc0 sc1"
                         :: "v"(gflags + mt * 32 + nt), "v"(one) : "memory");
        }
    }
}

__global__ __launch_bounds__(256, 1)
void k_fused(const unsigned short* __restrict__ w0hb,
             const unsigned short* __restrict__ w1hb,
             const unsigned short* __restrict__ w1ib,
             const float* __restrict__ bb1,
             unsigned short* __restrict__ xw,
             unsigned short* __restrict__ ring0,
             unsigned short* __restrict__ ring1,
             const float* __restrict__ c0,
             const unsigned short* __restrict__ hA0,
             const unsigned short* __restrict__ hA1,
             float* __restrict__ hn, float* __restrict__ cn,
             unsigned* __restrict__ gflags)
{
    __shared__ alignas(16) char smem[4 * 64 * PLDS_W * 4];   // 69632 B (gemm uses 32 KB)
    const int bid = blockIdx.x;
    if (bid < NSCAN) {
        scan_body<0>(w0hb, xw, c0, hA0, ring0, hn, cn, nullptr, bid, smem);
    } else if (bid < NSCAN + NGEMM) {
        gemm_body(ring0, w1ib, bb1, xw, gflags, bid - NSCAN, smem);
    } else {
        scan_body<1>(w1hb, xw, c0 + BATCH * HDIM, hA1, ring1,
                     hn + BATCH * HDIM, cn + BATCH * HDIM,
                     gflags, bid - NSCAN - NGEMM, smem);
    }
}

// ---------------- decode + log_softmax ----------------
__global__ __launch_bounds__(256)
void k_decode(const float* __restrict__ h1,
              const float* __restrict__ wdec,
              const float* __restrict__ bdec,
              float* __restrict__ out)
{
    __shared__ float hs[HDIM];
    __shared__ float ls[NINPUT];
    __shared__ float red[256];
    const int r = blockIdx.x, tid = threadIdx.x;
    reinterpret_cast<float4*>(hs)[tid] = reinterpret_cast<const float4*>(h1 + (size_t)r * HDIM)[tid];
    __syncthreads();
#pragma unroll
    for (int rep = 0; rep < 2; rep++) {
        int n = tid + rep * 256;
        float s = bdec[n];
        const float4* w4 = reinterpret_cast<const float4*>(wdec + (size_t)n * HDIM);
        for (int k = 0; k < HDIM / 4; k++) {
            float4 w = w4[k];
            float4 h4 = reinterpret_cast<const float4*>(hs)[k];
            s += w.x * h4.x + w.y * h4.y + w.z * h4.z + w.w * h4.w;
        }
        ls[n] = s;
    }
    __syncthreads();
    red[tid] = fmaxf(ls[tid], ls[tid + 256]);
    __syncthreads();
    for (int s2 = 128; s2 > 0; s2 >>= 1) {
        if (tid < s2) red[tid] = fmaxf(red[tid], red[tid + s2]);
        __syncthreads();
    }
    float M = red[0];
    __syncthreads();
    red[tid] = __expf(ls[tid] - M) + __expf(ls[tid + 256] - M);
    __syncthreads();
    for (int s2 = 128; s2 > 0; s2 >>= 1) {
        if (tid < s2) red[tid] += red[tid + s2];
        __syncthreads();
    }
    float lse = M + __logf(red[0]);
    out[(size_t)r * NINPUT + tid] = ls[tid] - lse;
    out[(size_t)r * NINPUT + tid + 256] = ls[tid + 256] - lse;
}

// ---------------- host launcher ----------------
extern "C" void kernel_launch(void* const* d_in, const int* in_sizes, int n_in,
                              void* d_out, int out_size, void* d_ws, size_t ws_size,
                              hipStream_t stream)
{
    const float* x    = (const float*)d_in[0];
    const float* h0   = (const float*)d_in[1];
    const float* c0   = (const float*)d_in[2];
    const float* wih0 = (const float*)d_in[3];
    const float* whh0 = (const float*)d_in[4];
    const float* bih0 = (const float*)d_in[5];
    const float* bhh0 = (const float*)d_in[6];
    const float* wih1 = (const float*)d_in[7];
    const float* whh1 = (const float*)d_in[8];
    const float* bih1 = (const float*)d_in[9];
    const float* bhh1 = (const float*)d_in[10];
    const float* wdec = (const float*)d_in[11];
    const float* bdec = (const float*)d_in[12];
    float* out = (float*)d_out;

    char* ws = (char*)d_ws;
    size_t off = 0;
    auto alloc = [&](size_t bytes) -> void* {
        void* p = ws + off;
        off += (bytes + 255) & ~(size_t)255;
        return p;
    };
    const size_t ring_bytes = (size_t)TSTEPS * BATCH * HDIM * 2;   // 33.5 MB

    unsigned short* xw    = (unsigned short*)alloc((size_t)BATCH * TSTEPS * G4 * 2);   // 134.2 MB time-major
    unsigned short* ring0 = (unsigned short*)alloc(ring_bytes);                        // 33.5 MB time-major
    unsigned short* w0hb  = (unsigned short*)alloc((size_t)G4 * HDIM * 2);
    unsigned short* w1ib  = (unsigned short*)alloc((size_t)G4 * HDIM * 2);
    unsigned short* w1hb  = (unsigned short*)alloc((size_t)G4 * HDIM * 2);
    float*          bb0   = (float*)alloc(G4 * 4);
    float*          bb1   = (float*)alloc(G4 * 4);
    unsigned short* hA0   = (unsigned short*)alloc(BATCH * HDIM * 2);
    unsigned short* hA1   = (unsigned short*)alloc(BATCH * HDIM * 2);
    unsigned*       gflags = (unsigned*)alloc(128 * 32 * 4);
    // ring1 overlays xb + w0ib (dead after gemm0) + explicit pad
    unsigned short* xb    = (unsigned short*)alloc((size_t)TSTEPS * BATCH * NINPUT * 2); // 16.8 MB
    unsigned short* w0ib  = (unsigned short*)alloc((size_t)G4 * NINPUT * 2);             // 4.2 MB
    unsigned short* ring1 = xb;
    {
        size_t have = (size_t)TSTEPS * BATCH * NINPUT * 2 + (size_t)G4 * NINPUT * 2;
        if (ring_bytes > have) alloc(ring_bytes - have);                                 // 12.6 MB pad
    }

    const long ring_n4 = (long)ring_bytes / 16;

    // single prologue kernel: conversions + biases + h0 + ring0 poison + gflags clear
    k_prep_all<<<2048, 256, 0, stream>>>(x, xb, wih0, w0ib, whh0, w0hb,
                                         wih1, w1ib, whh1, w1hb,
                                         bih0, bhh0, bb0, bih1, bhh1, bb1,
                                         h0, hA0, hA1, (u32x4*)ring0, gflags);

    const int M = BATCH * TSTEPS;
    // layer 0 input projection (time-major rows): xw0 = xb @ wih0^T + (bih0+bhh0)
    k_gemm_bt<<<(M / BM) * (G4 / BN), 256, 0, stream>>>(xb, w0ib, bb0, xw, M, G4, NINPUT);

    // xb/w0ib now dead -> poison ring1 (full-T sentinel ring for scan1)
    k_poison<<<2048, 256, 0, stream>>>((u32x4*)ring1, ring_n4);

    // fused pipeline: scan0 | gemm1 (xw overwritten in place) | scan1
    k_fused<<<NSCAN + NGEMM + NSCAN, 256, 0, stream>>>(
        w0hb, w1hb, w1ib, bb1, xw, ring0, ring1, c0, hA0, hA1,
        out + 32768,
        out + 32768 + 2 * BATCH * HDIM,
        gflags);

    // decode from fp32 final h of layer 1
    k_decode<<<BATCH, 256, 0, stream>>>(out + 32768 + BATCH * HDIM, wdec, bdec, out);
}